// Round 14
// baseline (3940.719 us; speedup 1.0000x reference)
//
#include <hip/hip_runtime.h>
#include <cstdint>
#include <cstddef>

typedef unsigned short u16;
typedef unsigned int   u32;
typedef unsigned long long u64;

#define S_LEN 100
#define B_SZ  512
#define H_LS  300
#define NHOP  3
#define NC_   7
#define BM1   511   // B-1
#define NBD4  120   // lstm9 blocks per dir (8 rowT x 15 colT)

using bf16x8 = __attribute__((ext_vector_type(8))) short;
using f32x4  = __attribute__((ext_vector_type(4))) float;

__device__ __forceinline__ float u2f(u16 u) {
  union { u32 i; float f; } x; x.i = ((u32)u) << 16; return x.f;
}
__device__ __forceinline__ u16 f2u(float f) {
  u32 bits = __float_as_uint(f);
  bits += 0x7fffu + ((bits >> 16) & 1u);   // RNE
  return (u16)(bits >> 16);
}
__device__ __forceinline__ float sigm(float x) { return 1.0f / (1.0f + expf(-x)); }

// ------------------------------------------------------------------
// dtype detect on emb raw bits (validated r1->r2)
// ------------------------------------------------------------------
__global__ void detect_k(const u32* __restrict__ raw, int* __restrict__ flag) {
  __shared__ int cnt;
  if (threadIdx.x == 0) cnt = 0;
  __syncthreads();
  u32 w = raw[threadIdx.x];
  u32 lo = w & 0xFFFFu;
  int e = (int)((lo >> 7) & 0xFF);
  int pl = (lo == 0u || (e >= 0x70 && e <= 0x8E)) ? 1 : 0;
  atomicAdd(&cnt, pl);
  __syncthreads();
  if (threadIdx.x == 0) *flag = (cnt >= 192) ? 1 : 0;   // 1 = bf16 device data
}

// ------------------------------------------------------------------
// normalize ALL float params -> f32 mirror allf (validated r6/r7)
// ------------------------------------------------------------------
#define NF_NSEG 28
#define NF_TOT  1748007
struct NormFArgs { const void* src[NF_NSEG]; const int* flag; float* dst; };

__global__ __launch_bounds__(256) void norm_f32(NormFArgs a) {
  const int P[NF_NSEG + 1] = {
    0,360000,720000,1080000,1440000,1441200,1442400,1443600,
    1444800,1474800,1504800,1505100,1505400,1535400,1565400,1565700,
    1566000,1626000,1626100,1656100,1686100,1716100,1746100,1746400,
    1746700,1747000,1747300,1748000,1748007};
  int fl = *a.flag;
  int stride = gridDim.x * 256;
  for (int i = blockIdx.x * 256 + threadIdx.x; i < NF_TOT; i += stride) {
    int s = 0;
    while (i >= P[s + 1]) ++s;
    int k = i - P[s];
    float v = fl ? u2f(((const u16*)a.src[s])[k]) : ((const float*)a.src[s])[k];
    a.dst[i] = v;
  }
}
#define AF_LWIH_F 0
#define AF_LWHH_F 360000
#define AF_LWIH_B 720000
#define AF_LWHH_B 1080000
#define AF_LBIH_F 1440000
#define AF_LBHH_F 1441200
#define AF_LBIH_B 1442400
#define AF_LBHH_B 1443600
#define AF_GWIH_F 1444800
#define AF_GWHH_F 1474800
#define AF_GBIH_F 1504800
#define AF_GBHH_F 1505100
#define AF_GWIH_B 1505400
#define AF_GWHH_B 1535400
#define AF_GBIH_B 1565400
#define AF_GBHH_B 1565700
#define AF_LIN1W  1566000
#define AF_LIN1B  1626000
#define AF_ATTWR  1626100
#define AF_ATTUR  1656100
#define AF_ATTW   1686100
#define AF_ATTU   1716100
#define AF_ATTBR  1746100
#define AF_ATTBUR 1746400
#define AF_ATTBW  1746700
#define AF_ATTBU  1747000
#define AF_CLSW   1747300
#define AF_CLSB   1748000

// ------------------------------------------------------------------
// transpose 100x100 chunks to k-major: gWhh (2x3) + att Ur/U (3 hops x2)
// ------------------------------------------------------------------
__global__ void transp_k(const float* __restrict__ allf, float* __restrict__ wt) {
  int idx = blockIdx.x * 256 + threadIdx.x;
  if (idx >= 120000) return;
  int seg = idx / 10000;
  int rem = idx - seg * 10000;
  int k = rem / 100, j = rem - (rem / 100) * 100;
  int srcbase;
  if (seg < 3)      srcbase = AF_GWHH_F + seg * 10000;
  else if (seg < 6) srcbase = AF_GWHH_B + (seg - 3) * 10000;
  else if (seg < 9) srcbase = AF_ATTUR + (seg - 6) * 10000;
  else              srcbase = AF_ATTU  + (seg - 9) * 10000;
  wt[seg * 10000 + k * 100 + j] = allf[srcbase + j * 100 + k];
}

// ------------------------------------------------------------------
// LSTM weights -> wL2[dir][c=j*4+g][k'=0..639] bf16 (K padded 2x320)
// Plus bias sums bsum[dir][g*300+j].
// ------------------------------------------------------------------
__global__ void tr_lstm2(const float* __restrict__ allf, u16* __restrict__ wL2,
                         float* __restrict__ bsum) {
  int idx = blockIdx.x * 256 + threadIdx.x;
  if (idx < 1536000) {
    int dir = idx / 768000;
    int rem = idx - dir * 768000;
    int c = rem / 640, kp = rem - (rem / 640) * 640;
    int j = c >> 2, g = c & 3;
    float v = 0.f;
    if (kp < 320) {
      if (kp < 300)
        v = allf[(dir ? AF_LWIH_B : AF_LWIH_F) + (g * 300 + j) * 300 + kp];
    } else {
      int k2 = kp - 320;
      if (k2 < 300)
        v = allf[(dir ? AF_LWHH_B : AF_LWHH_F) + (g * 300 + j) * 300 + k2];
    }
    wL2[idx] = f2u(v);
  } else if (idx < 1538400) {
    int i2 = idx - 1536000;
    int dir = i2 / 1200, gj = i2 - (i2 / 1200) * 1200;
    bsum[i2] = allf[(dir ? AF_LBIH_B : AF_LBIH_F) + gj]
             + allf[(dir ? AF_LBHH_B : AF_LBHH_F) + gj];
  }
}

// ------------------------------------------------------------------
// gather emb row-major bf16: xallR[t][r][320] (pad 300..319 = 0)
// ------------------------------------------------------------------
__global__ __launch_bounds__(256) void xgat2(const int* __restrict__ sents,
                                             const void* __restrict__ emb,
                                             const int* __restrict__ flag,
                                             u16* __restrict__ xallR) {
  __shared__ int toks[64];
  int tid = threadIdx.x;
  int r0 = blockIdx.x * 64, t = blockIdx.y;
  int fl = *flag;
  if (tid < 64) toks[tid] = sents[(r0 + tid) * S_LEN + t];
  __syncthreads();
  for (int idx = tid; idx < 64 * 320; idx += 256) {
    int r = idx / 320, k = idx - (idx / 320) * 320;
    u16 v = 0;
    if (k < 300) {
      size_t si = (size_t)toks[r] * 300 + k;
      v = fl ? ((const u16*)emb)[si] : f2u(((const float*)emb)[si]);
    }
    xallR[((size_t)t * 512 + r0 + r) * 320 + k] = v;
  }
}

// ------------------------------------------------------------------
// LSTM persistent MFMA scan v9: grid (8 rowT[64], 15 colT[80], 2 dir)
// = 240 blocks (1/CU, 125KB LDS), 512 thr = 8 waves.
// wave w: row-frag rf=w&3 (16 rows), k-half kh=w>>2 (kh0 = x seg,
// kh1 = h seg). A-frags prefetched 1-deep; W slice resident in LDS.
// Gate combine: kh0 writes Gs, kh1 adds (2 block barriers). Gs stride
// 85 (odd) kills exchange conflicts. Epoch-flag grid barrier per dir.
// MFMA fragment convention == r2/r3 bit-identical-validated scheme.
// ------------------------------------------------------------------
struct Lstm9Args {
  const int* lens;
  const u16* xallR;     // [100][512][320] bf16
  const u16* wL2;       // [dir][1200][640] bf16
  const float* bsum;    // [dir][1200] (g*300+j)
  float* hbufR;         // [2 par][2 dir][512][320] f32 (pad j>=300 stays 0)
  float* maxb;          // [512][600]
  int* cnt;             // per-dir: ctr at dir*32, flag at dir*32+16
};

__global__ __launch_bounds__(512, 1) void lstm9(Lstm9Args a) {
  __shared__ u16   WLh[80 * 640];    // 102400 B, swizzled: byte^=((cc&7)<<4)
  __shared__ float Gs[64 * 85];      // 21760 B
  const int tid = threadIdx.x;
  const int r0  = blockIdx.x * 64;
  const int ct  = blockIdx.y;        // j0 = ct*20
  const int dir = blockIdx.z;

  // ---- stage W slice once
  {
    const u64* wsrc = (const u64*)(a.wL2 + (size_t)dir * 768000 + (size_t)ct * 80 * 640);
    for (int i = tid; i < 80 * 160; i += 512) {
      int cc = i / 160, kw = i - (i / 160) * 160;
      u64 v = wsrc[(size_t)cc * 160 + kw];
      *(u64*)((char*)WLh + cc * 1280 + ((kw * 8) ^ ((cc & 7) << 4))) = v;
    }
  }

  const int w  = tid >> 6;
  const int rf = w & 3;              // row-frag (16 rows)
  const int kh = w >> 2;             // 0: x seg, 1: h seg
  const int l  = tid & 63;
  const int lr = l & 15;
  const int aq = l >> 4;
  const int arow = r0 + rf * 16 + lr;

  // ---- per-thread cells: up to 3 of (64 rows x 20 j), idx = tid + i*512
  float cq[3] = {0.f, 0.f, 0.f}, hq[3] = {0.f, 0.f, 0.f};
  float mxv[3] = {-INFINITY, -INFINITY, -INFINITY};
  float bsv[3][4];
  int lenv[3];
  #pragma unroll
  for (int i = 0; i < 3; ++i) {
    int idx = tid + i * 512;
    if (idx < 1280) {
      int r = idx / 20, jj = idx - (idx / 20) * 20;
      int j = ct * 20 + jj;
      lenv[i] = a.lens[r0 + r];
      #pragma unroll
      for (int g = 0; g < 4; ++g) bsv[i][g] = a.bsum[dir * 1200 + g * 300 + j];
    } else {
      lenv[i] = 0;
      bsv[i][0] = bsv[i][1] = bsv[i][2] = bsv[i][3] = 0.f;
    }
  }

  int* cptr = a.cnt + dir * 32;
  int* fptr = a.cnt + dir * 32 + 16;
  __syncthreads();

  for (int s = 0; s < S_LEN; ++s) {
    const int tt  = dir ? (S_LEN - 1 - s) : s;
    const int cur = s & 1, nxt = cur ^ 1;

    f32x4 acc0 = {0,0,0,0}, acc1 = {0,0,0,0}, acc2 = {0,0,0,0},
          acc3 = {0,0,0,0}, acc4 = {0,0,0,0};

    if (kh == 0) {
      const u16* xrow = a.xallR + ((size_t)tt * 512 + arow) * 320 + aq * 8;
      bf16x8 Af = *(const bf16x8*)(xrow);
      #pragma unroll
      for (int ks = 0; ks < 10; ++ks) {
        bf16x8 An = (ks < 9) ? *(const bf16x8*)(xrow + (ks + 1) * 32) : Af;
        #pragma unroll
        for (int cf = 0; cf < 5; ++cf) {
          int cc = cf * 16 + lr;
          bf16x8 Bf = *(const bf16x8*)((const char*)WLh + cc * 1280 +
                                       ((ks * 64 + aq * 16) ^ ((cc & 7) << 4)));
          f32x4& ac = (cf == 0) ? acc0 : (cf == 1) ? acc1 : (cf == 2) ? acc2
                    : (cf == 3) ? acc3 : acc4;
          ac = __builtin_amdgcn_mfma_f32_16x16x32_bf16(Af, Bf, ac, 0, 0, 0);
        }
        Af = An;
      }
    } else {
      const float* hrow = a.hbufR + (((size_t)cur * 2 + dir) * 512 + arow) * 320 + aq * 8;
      float4 h0 = *(const float4*)hrow;
      float4 h1 = *(const float4*)(hrow + 4);
      #pragma unroll
      for (int ks = 0; ks < 10; ++ks) {
        float4 n0, n1;
        if (ks < 9) {
          n0 = *(const float4*)(hrow + (ks + 1) * 32);
          n1 = *(const float4*)(hrow + (ks + 1) * 32 + 4);
        }
        union { u32 u[4]; bf16x8 v; } pk;
        pk.u[0] = ((u32)f2u(h0.y) << 16) | (u32)f2u(h0.x);
        pk.u[1] = ((u32)f2u(h0.w) << 16) | (u32)f2u(h0.z);
        pk.u[2] = ((u32)f2u(h1.y) << 16) | (u32)f2u(h1.x);
        pk.u[3] = ((u32)f2u(h1.w) << 16) | (u32)f2u(h1.z);
        bf16x8 Af = pk.v;
        #pragma unroll
        for (int cf = 0; cf < 5; ++cf) {
          int cc = cf * 16 + lr;
          bf16x8 Bf = *(const bf16x8*)((const char*)WLh + cc * 1280 +
                                       (((ks + 10) * 64 + aq * 16) ^ ((cc & 7) << 4)));
          f32x4& ac = (cf == 0) ? acc0 : (cf == 1) ? acc1 : (cf == 2) ? acc2
                    : (cf == 3) ? acc3 : acc4;
          ac = __builtin_amdgcn_mfma_f32_16x16x32_bf16(Af, Bf, ac, 0, 0, 0);
        }
        if (ks < 9) { h0 = n0; h1 = n1; }
      }
    }

    // ---- gate combine: kh0 writes, kh1 adds (C row=(l>>4)*4+reg, col=l&15)
    if (kh == 0) {
      #pragma unroll
      for (int rr = 0; rr < 4; ++rr) {
        int gr = (rf * 16 + aq * 4 + rr) * 85;
        Gs[gr + 0 * 16 + lr] = acc0[rr];
        Gs[gr + 1 * 16 + lr] = acc1[rr];
        Gs[gr + 2 * 16 + lr] = acc2[rr];
        Gs[gr + 3 * 16 + lr] = acc3[rr];
        Gs[gr + 4 * 16 + lr] = acc4[rr];
      }
    }
    __syncthreads();
    if (kh == 1) {
      #pragma unroll
      for (int rr = 0; rr < 4; ++rr) {
        int gr = (rf * 16 + aq * 4 + rr) * 85;
        Gs[gr + 0 * 16 + lr] += acc0[rr];
        Gs[gr + 1 * 16 + lr] += acc1[rr];
        Gs[gr + 2 * 16 + lr] += acc2[rr];
        Gs[gr + 3 * 16 + lr] += acc3[rr];
        Gs[gr + 4 * 16 + lr] += acc4[rr];
      }
    }
    __syncthreads();

    // ---- cell update (gate order i,f,g,o at cols jj*4+g)
    #pragma unroll
    for (int i = 0; i < 3; ++i) {
      int idx = tid + i * 512;
      if (idx < 1280) {
        int r = idx / 20, jj = idx - (idx / 20) * 20;
        bool m = tt < lenv[i];
        if (m) {
          float gi = Gs[r * 85 + jj * 4 + 0] + bsv[i][0];
          float gf = Gs[r * 85 + jj * 4 + 1] + bsv[i][1];
          float gg = Gs[r * 85 + jj * 4 + 2] + bsv[i][2];
          float go = Gs[r * 85 + jj * 4 + 3] + bsv[i][3];
          cq[i] = sigm(gf) * cq[i] + sigm(gi) * tanhf(gg);
          hq[i] = sigm(go) * tanhf(cq[i]);
          mxv[i] = fmaxf(mxv[i], hq[i]);
        } else {
          mxv[i] = fmaxf(mxv[i], 0.f);
        }
        a.hbufR[(((size_t)nxt * 2 + dir) * 512 + r0 + r) * 320 + ct * 20 + jj] = hq[i];
      }
    }

    // ---- per-dir grid barrier: RMW arrival + epoch-flag spin
    __syncthreads();
    if (tid == 0) {
      __threadfence();
      int old = __hip_atomic_fetch_add(cptr, 1, __ATOMIC_ACQ_REL, __HIP_MEMORY_SCOPE_AGENT);
      if (old == NBD4 * (s + 1) - 1) {
        __hip_atomic_store(fptr, s + 1, __ATOMIC_RELEASE, __HIP_MEMORY_SCOPE_AGENT);
      } else {
        while (__hip_atomic_load(fptr, __ATOMIC_ACQUIRE, __HIP_MEMORY_SCOPE_AGENT) < s + 1)
          __builtin_amdgcn_s_sleep(2);
      }
      __threadfence();
    }
    __syncthreads();
  }

  // ---- maxpool writeout
  #pragma unroll
  for (int i = 0; i < 3; ++i) {
    int idx = tid + i * 512;
    if (idx < 1280) {
      int r = idx / 20, jj = idx - (idx / 20) * 20;
      a.maxb[(size_t)(r0 + r) * 600 + dir * 300 + ct * 20 + jj] = mxv[i];
    }
  }
}

// ------------------------------------------------------------------
// s_utt = tanh(maxpl @ lin1_W^T + lin1_b)   [512,100]
// ------------------------------------------------------------------
__global__ __launch_bounds__(128) void sutt_k(const float* __restrict__ maxb,
                                              const float* __restrict__ W,
                                              const float* __restrict__ bb,
                                              float* __restrict__ sutt) {
  int b = blockIdx.x, tid = threadIdx.x;
  __shared__ float mx[600];
  for (int i = tid; i < 600; i += 128) mx[i] = maxb[b * 600 + i];
  __syncthreads();
  if (tid < 100) {
    float acc = bb[tid];
    const float* wr = W + tid * 600;
    for (int k = 0; k < 600; ++k) acc += mx[k] * wr[k];
    sutt[b * 100 + tid] = tanhf(acc);
  }
}

// ------------------------------------------------------------------
// GRU x-projection: xg[dir][t][row][300] f32 (incl. bih)
// ------------------------------------------------------------------
__global__ __launch_bounds__(256) void gxg3(const float* __restrict__ sutt,
                                            const float* __restrict__ Wf, const float* __restrict__ bf_,
                                            const float* __restrict__ Wb, const float* __restrict__ bb_,
                                            float* __restrict__ xg) {
  __shared__ float bts[32][101];
  int tid = threadIdx.x;
  int rt = blockIdx.x * 32, t = blockIdx.y, dir = blockIdx.z;
  int tin = dir ? (39 - t) : t;
  for (int idx = tid; idx < 3200; idx += 256) {
    int r = idx / 100, k = idx - r * 100, row = rt + r;
    float v = 0.f;
    if (row < BM1) {
      int srow = row + 1 - 40 + tin;
      if (srow >= 0) v = sutt[srow * 100 + k];
    }
    bts[r][k] = v;
  }
  __syncthreads();
  const float* Wm = dir ? Wb : Wf;
  const float* bm = dir ? bb_ : bf_;
  for (int o = tid; o < 9600; o += 256) {
    int r = o & 31, g = o >> 5;
    float acc = bm[g];
    const float* wr = Wm + g * 100;
    const float* br = bts[r];
    for (int k = 0; k < 100; ++k) acc += br[k] * wr[k];
    int row = rt + r;
    if (row < BM1) xg[(((size_t)dir * 40 + t) * BM1 + row) * 300 + g] = acc;
  }
}

// ------------------------------------------------------------------
// GRU scan v4 (validated r9)
// ------------------------------------------------------------------
struct Gru4Args {
  const float* wt;
  const float* bhh[2];
  const float* xg;
  float* memf; float* memb;
};

__global__ __launch_bounds__(512) void gru4(Gru4Args a) {
  __shared__ float WT[30000];
  __shared__ float hl[2][4][104];
  int tid = threadIdx.x, rt = blockIdx.x * 4, dir = blockIdx.y;
  const float* src = a.wt + dir * 30000;
  for (int i = tid; i < 30000; i += 512) WT[i] = src[i];
  for (int i = tid; i < 832; i += 512) ((float*)hl)[i] = 0.f;
  int r = tid / 100, j = tid - r * 100;
  int row = rt + r;
  bool act = (tid < 400) && (row < BM1);
  const float* bhh = a.bhh[dir];
  float xr = 0.f, xz = 0.f, xn = 0.f;
  if (act) {
    size_t xb = ((size_t)(dir * 40) * BM1 + row) * 300;
    xr = a.xg[xb + j]; xz = a.xg[xb + 100 + j]; xn = a.xg[xb + 200 + j];
  }
  float hprev = 0.f;
  __syncthreads();
  for (int t = 0; t < 40; ++t) {
    int nxt = (t + 1) & 1, cur = t & 1;
    float xr2 = 0.f, xz2 = 0.f, xn2 = 0.f;
    if (act && t < 39) {
      size_t xb = ((size_t)(dir * 40 + t + 1) * BM1 + row) * 300;
      xr2 = a.xg[xb + j]; xz2 = a.xg[xb + 100 + j]; xn2 = a.xg[xb + 200 + j];
    }
    float v = 0.f;
    if (act) {
      float hr = bhh[j], hz = bhh[100 + j], hn = bhh[200 + j];
      const float* w0 = WT + j;
      const float* hrow = hl[cur][r];
      for (int k = 0; k < 100; ++k) {
        float hv = hrow[k];
        hr += hv * w0[k * 100];
        hz += hv * w0[10000 + k * 100];
        hn += hv * w0[20000 + k * 100];
      }
      float rg_ = sigm(xr + hr), zg = sigm(xz + hz);
      float ng = tanhf(xn + rg_ * hn);
      v = (1.f - zg) * ng + zg * hprev;
      int tin = dir ? (39 - t) : t;
      (dir ? a.memb : a.memf)[((size_t)tin * BM1 + row) * 100 + j] = v;
    }
    if (tid < 400) hl[nxt][r][j] = v;
    hprev = v;
    __syncthreads();
    xr = xr2; xz = xz2; xn = xn2;
  }
}

// mem = bt + mem_f + mem_b
__global__ void memcomb(const float* __restrict__ memf, const float* __restrict__ memb,
                        const float* __restrict__ sutt, float* __restrict__ memm) {
  int idx = blockIdx.x * 256 + threadIdx.x;
  if (idx >= 40 * BM1 * 100) return;
  int j = idx % 100; int rem = idx / 100; int row = rem % BM1; int t = rem / BM1;
  float v = memf[idx] + memb[idx];
  int sidx = row + 1 - 40 + t;
  if (sidx >= 0) v += sutt[sidx * 100 + j];
  memm[idx] = v;
}

__global__ void epsinit(const float* __restrict__ sutt, float* __restrict__ eps) {
  int idx = blockIdx.x * 256 + threadIdx.x;
  if (idx < BM1 * 100) eps[idx] = sutt[idx + 100];
}

// attention scores + softmax -> gates + attn output (f32)
__global__ __launch_bounds__(64) void attnsc(const float* __restrict__ eps,
                                             const float* __restrict__ memm,
                                             float* __restrict__ gatesw,
                                             float* __restrict__ outat) {
  int row = blockIdx.x, k = threadIdx.x;
  __shared__ float el[100];
  for (int i = k; i < 100; i += 64) el[i] = eps[row * 100 + i];
  __syncthreads();
  float val = -INFINITY;
  if (k < 40) {
    if (row + 1 - 40 + k >= 0) {
      const float* mrow = memm + ((size_t)k * BM1 + row) * 100;
      float s = 0.f;
      for (int d = 0; d < 100; ++d) s += el[d] * mrow[d];
      val = s;
    } else val = -1e10f;
  }
  float mx = val;
  for (int off = 32; off > 0; off >>= 1) mx = fmaxf(mx, __shfl_xor(mx, off));
  float ex = (k < 40) ? expf(val - mx) : 0.f;
  float sm = ex;
  for (int off = 32; off > 0; off >>= 1) sm += __shfl_xor(sm, off);
  if (k < 40) {
    float sc = ex / sm;
    gatesw[k * BM1 + row] = sc;
    outat[row * 40 + k] = sc;
  }
}

// cr/cw precompute GEMM: grid (16, 40, 2)
__global__ __launch_bounds__(256) void crcw3(const float* __restrict__ memm,
                                             const float* __restrict__ Wr, const float* __restrict__ br,
                                             const float* __restrict__ Ww, const float* __restrict__ bw,
                                             float* __restrict__ crb, float* __restrict__ cwb) {
  __shared__ float ml[32][101];
  int tid = threadIdx.x;
  int rt = blockIdx.x * 32, t = blockIdx.y, which = blockIdx.z;
  for (int idx = tid; idx < 3200; idx += 256) {
    int r = idx / 100, k = idx - r * 100; int row = rt + r;
    ml[r][k] = (row < BM1) ? memm[((size_t)t * BM1 + row) * 100 + k] : 0.f;
  }
  __syncthreads();
  const float* Wm = which ? Ww : Wr;
  const float* bm = which ? bw : br;
  float* ob = which ? cwb : crb;
  for (int o = tid; o < 3200; o += 256) {
    int r = o & 31, hh = o >> 5;
    float acc = bm[hh];
    const float* wr = Wm + hh * 100;
    for (int k = 0; k < 100; ++k) acc += ml[r][k] * wr[k];
    int row = rt + r;
    if (row < BM1) ob[((size_t)t * BM1 + row) * 100 + hh] = acc;
  }
}

// ------------------------------------------------------------------
// AttnGRU scan v4 (validated r9)
// ------------------------------------------------------------------
struct Att4Args {
  const float* urT; const float* uT;
  const float* bur; const float* bu;
  const float* crb; const float* cwb;
  const float* gatesw; float* eps;
};

__global__ __launch_bounds__(512) void attscan4(Att4Args a) {
  __shared__ float UrT[10000];
  __shared__ float UT[10000];
  __shared__ float hl[2][4][104];
  int tid = threadIdx.x, rt = blockIdx.x * 4;
  for (int i = tid; i < 10000; i += 512) { UrT[i] = a.urT[i]; UT[i] = a.uT[i]; }
  for (int i = tid; i < 832; i += 512) ((float*)hl)[i] = 0.f;
  int r = tid / 100, j = tid - r * 100;
  int row = rt + r;
  bool act = (tid < 400) && (row < BM1);
  float cr = 0.f, cw = 0.f, gw = 0.f;
  if (act) {
    size_t ix = (size_t)row * 100 + j;
    cr = a.crb[ix]; cw = a.cwb[ix]; gw = a.gatesw[row];
  }
  float hprev = 0.f;
  __syncthreads();
  for (int t = 0; t < 40; ++t) {
    int nxt = (t + 1) & 1, cur = t & 1;
    float cr2 = 0.f, cw2 = 0.f, gw2 = 0.f;
    if (act && t < 39) {
      size_t ix = ((size_t)(t + 1) * BM1 + row) * 100 + j;
      cr2 = a.crb[ix]; cw2 = a.cwb[ix]; gw2 = a.gatesw[(t + 1) * BM1 + row];
    }
    float v = 0.f;
    if (act) {
      float hr = a.bur[j], hu = a.bu[j];
      const float* hrow = hl[cur][r];
      for (int k = 0; k < 100; ++k) {
        float hv = hrow[k];
        hr += hv * UrT[k * 100 + j];
        hu += hv * UT[k * 100 + j];
      }
      float rg_ = sigm(cr + hr);
      float ht = tanhf(cw + rg_ * hu);
      v = gw * ht + (1.f - gw) * hprev;
    }
    if (tid < 400) hl[nxt][r][j] = v;
    hprev = v;
    __syncthreads();
    cr = cr2; cw = cw2; gw = gw2;
  }
  if (act) a.eps[(size_t)row * 100 + j] += hprev;
}

// classifier -> f32
__global__ __launch_bounds__(64) void cls_k(const float* __restrict__ sutt,
                                            const float* __restrict__ eps,
                                            const float* __restrict__ cW, const float* __restrict__ cb,
                                            float* __restrict__ outp) {
  int b = blockIdx.x, j = threadIdx.x;
  __shared__ float sl[100];
  for (int i = j; i < 100; i += 64) sl[i] = (b == 0) ? sutt[i] : eps[(b - 1) * 100 + i];
  __syncthreads();
  float lg = -INFINITY;
  if (j < 7) {
    lg = cb[j];
    const float* wr = cW + j * 100;
    for (int k = 0; k < 100; ++k) lg += sl[k] * wr[k];
  }
  float mx = lg;
  for (int off = 32; off > 0; off >>= 1) mx = fmaxf(mx, __shfl_xor(mx, off));
  float ex = (j < 7) ? expf(lg - mx) : 0.f;
  float sm = ex;
  for (int off = 32; off > 0; off >>= 1) sm += __shfl_xor(sm, off);
  if (j < 7) outp[b * 7 + j] = lg - mx - logf(sm);
}

// ------------------------------------------------------------------
extern "C" void kernel_launch(void* const* d_in, const int* in_sizes, int n_in,
                              void* d_out, int out_size, void* d_ws, size_t ws_size,
                              hipStream_t stream) {
  (void)n_in; (void)out_size; (void)ws_size;

  bool sigOrder = (in_sizes[7] == 360000);   // r4 evidence: dict order

  const void *p_sents, *p_lens, *p_emb;
  const void *p_lWih_f, *p_lWhh_f, *p_lbih_f, *p_lbhh_f;
  const void *p_lWih_b, *p_lWhh_b, *p_lbih_b, *p_lbhh_b;
  const void *p_gWih_f, *p_gWhh_f, *p_gbih_f, *p_gbhh_f;
  const void *p_gWih_b, *p_gWhh_b, *p_gbih_b, *p_gbhh_b;
  const void *p_lin1W, *p_lin1b;
  const void *p_attWr, *p_attUr, *p_attW, *p_attU;
  const void *p_attbr, *p_attbur, *p_attbw, *p_attbu;
  const void *p_clsW, *p_clsb;

  p_sents = d_in[0]; p_lens = d_in[1]; p_emb = d_in[2];
  p_lWih_f = d_in[3]; p_lWhh_f = d_in[4]; p_lbih_f = d_in[5]; p_lbhh_f = d_in[6];
  if (sigOrder) {
    p_lWih_b = d_in[7];  p_lWhh_b = d_in[8];  p_lbih_b = d_in[9];  p_lbhh_b = d_in[10];
    p_lin1W  = d_in[11]; p_lin1b  = d_in[12];
    p_gWih_f = d_in[13]; p_gWhh_f = d_in[14]; p_gbih_f = d_in[15]; p_gbhh_f = d_in[16];
    p_gWih_b = d_in[17]; p_gWhh_b = d_in[18]; p_gbih_b = d_in[19]; p_gbhh_b = d_in[20];
    p_attWr  = d_in[21]; p_attbr  = d_in[22]; p_attUr  = d_in[23]; p_attbur = d_in[24];
    p_attW   = d_in[25]; p_attbw  = d_in[26]; p_attU   = d_in[27]; p_attbu  = d_in[28];
    p_clsW   = d_in[29]; p_clsb   = d_in[30];
  } else {
    p_gWih_f = d_in[7];  p_gWhh_f = d_in[8];  p_gbih_f = d_in[9];  p_gbhh_f = d_in[10];
    p_lWih_b = d_in[11]; p_lWhh_b = d_in[12]; p_lbih_b = d_in[13]; p_lbhh_b = d_in[14];
    p_gWih_b = d_in[15]; p_gWhh_b = d_in[16]; p_gbih_b = d_in[17]; p_gbhh_b = d_in[18];
    p_lin1W  = d_in[19]; p_lin1b  = d_in[20];
    p_attWr  = d_in[21]; p_attUr  = d_in[22]; p_attW   = d_in[23]; p_attU   = d_in[24];
    p_attbr  = d_in[25]; p_attbur = d_in[26]; p_attbw  = d_in[27]; p_attbu  = d_in[28];
    p_clsW   = d_in[29]; p_clsb   = d_in[30];
  }

  char* wp = (char*)d_ws;
  auto carve = [&](size_t bytes) {
    char* p = wp;
    wp += (bytes + 255) & ~(size_t)255;
    return p;
  };
  int*   flag  = (int*)  carve(256);
  int*   cnt   = (int*)  carve(256);
  float* allf  = (float*)carve((size_t)NF_TOT * 4);
  float* wt    = (float*)carve((size_t)120000 * 4);
  u16*   wL2   = (u16*)  carve((size_t)1536000 * 2);
  float* bsum  = (float*)carve((size_t)2400 * 4);
  float* hbufR = (float*)carve((size_t)2 * 2 * 512 * 320 * 4);
  float* maxb  = (float*)carve((size_t)B_SZ * 600 * 4);
  float* sutt  = (float*)carve((size_t)B_SZ * 100 * 4);
  // big region: xallR (bf16, dead after lstm9) aliases xg+memf+memb
  size_t xg_sz   = (size_t)2 * 40 * BM1 * 300 * 4;
  size_t memf_sz = (size_t)40 * BM1 * 100 * 4;
  char*  big   = carve(xg_sz + 2 * memf_sz);
  u16*   xallR = (u16*)big;
  float* xg    = (float*)big;
  float* memf  = (float*)(big + xg_sz);
  float* memb  = (float*)(big + xg_sz + memf_sz);
  float* memm  = (float*)carve(memf_sz);
  float* gatesw= (float*)carve((size_t)40 * BM1 * 4);
  float* eps   = (float*)carve((size_t)BM1 * 100 * 4);
  float* crb   = xg;
  float* cwb   = xg + (size_t)40 * BM1 * 100;

  float* out_pred = (float*)d_out;
  float* out_attn = out_pred + (size_t)B_SZ * NC_;

  detect_k<<<1, 256, 0, stream>>>((const u32*)p_emb, flag);

  NormFArgs nf;
  {
    const void* srcs[NF_NSEG] = {
      p_lWih_f, p_lWhh_f, p_lWih_b, p_lWhh_b,
      p_lbih_f, p_lbhh_f, p_lbih_b, p_lbhh_b,
      p_gWih_f, p_gWhh_f, p_gbih_f, p_gbhh_f,
      p_gWih_b, p_gWhh_b, p_gbih_b, p_gbhh_b,
      p_lin1W,  p_lin1b,
      p_attWr,  p_attUr,  p_attW,   p_attU,
      p_attbr,  p_attbur, p_attbw,  p_attbu,
      p_clsW,   p_clsb };
    for (int i = 0; i < NF_NSEG; ++i) nf.src[i] = srcs[i];
    nf.flag = flag; nf.dst = allf;
  }
  norm_f32<<<2048, 256, 0, stream>>>(nf);
  transp_k<<<(120000 + 255) / 256, 256, 0, stream>>>(allf, wt);
  tr_lstm2<<<(1538400 + 255) / 256, 256, 0, stream>>>(allf, wL2, bsum);
  xgat2<<<dim3(8, 100), 256, 0, stream>>>((const int*)p_sents, p_emb, flag, xallR);

  hipMemsetAsync(cnt, 0, 256, stream);
  hipMemsetAsync(hbufR, 0, (size_t)2 * 2 * 512 * 320 * 4, stream);

  Lstm9Args la;
  la.lens = (const int*)p_lens;
  la.xallR = xallR; la.wL2 = wL2; la.bsum = bsum;
  la.hbufR = hbufR; la.maxb = maxb; la.cnt = cnt;
  lstm9<<<dim3(8, 15, 2), 512, 0, stream>>>(la);

  sutt_k<<<512, 128, 0, stream>>>(maxb, allf + AF_LIN1W, allf + AF_LIN1B, sutt);

  gxg3<<<dim3(16, 40, 2), 256, 0, stream>>>(sutt,
      allf + AF_GWIH_F, allf + AF_GBIH_F,
      allf + AF_GWIH_B, allf + AF_GBIH_B, xg);

  Gru4Args ga;
  ga.wt = wt;
  ga.bhh[0] = allf + AF_GBHH_F; ga.bhh[1] = allf + AF_GBHH_B;
  ga.xg = xg; ga.memf = memf; ga.memb = memb;
  gru4<<<dim3(128, 2), 512, 0, stream>>>(ga);

  memcomb<<<(40 * BM1 * 100 + 255) / 256, 256, 0, stream>>>(memf, memb, sutt, memm);
  epsinit<<<(BM1 * 100 + 255) / 256, 256, 0, stream>>>(sutt, eps);

  for (int hop = 0; hop < NHOP; ++hop) {
    attnsc<<<BM1, 64, 0, stream>>>(eps, memm, gatesw, out_attn + (size_t)hop * BM1 * 40);
    crcw3<<<dim3(16, 40, 2), 256, 0, stream>>>(memm,
        allf + AF_ATTWR + hop * 10000, allf + AF_ATTBR + hop * 100,
        allf + AF_ATTW  + hop * 10000, allf + AF_ATTBW + hop * 100, crb, cwb);
    Att4Args aa;
    aa.urT = wt + 60000 + hop * 10000;
    aa.uT  = wt + 90000 + hop * 10000;
    aa.bur = allf + AF_ATTBUR + hop * 100;
    aa.bu  = allf + AF_ATTBU  + hop * 100;
    aa.crb = crb; aa.cwb = cwb;
    aa.gatesw = gatesw; aa.eps = eps;
    attscan4<<<128, 512, 0, stream>>>(aa);
  }

  cls_k<<<512, 64, 0, stream>>>(sutt, eps, allf + AF_CLSW, allf + AF_CLSB, out_pred);
}

// Round 15
// 3716.403 us; speedup vs baseline: 1.0604x; 1.0604x over previous
//
#include <hip/hip_runtime.h>
#include <cstdint>
#include <cstddef>

typedef unsigned short u16;
typedef unsigned int   u32;
typedef unsigned long long u64;

#define S_LEN 100
#define B_SZ  512
#define H_LS  300
#define NHOP  3
#define NC_   7
#define BM1   511   // B-1
#define GRPSZ 15    // lstm10 barrier group size (col-tiles per row-tile)

using bf16x8 = __attribute__((ext_vector_type(8))) short;
using f32x4  = __attribute__((ext_vector_type(4))) float;

__device__ __forceinline__ float u2f(u16 u) {
  union { u32 i; float f; } x; x.i = ((u32)u) << 16; return x.f;
}
__device__ __forceinline__ u16 f2u(float f) {
  u32 bits = __float_as_uint(f);
  bits += 0x7fffu + ((bits >> 16) & 1u);   // RNE
  return (u16)(bits >> 16);
}
__device__ __forceinline__ float sigm(float x) { return 1.0f / (1.0f + expf(-x)); }

// ------------------------------------------------------------------
// dtype detect on emb raw bits (validated r1->r2)
// ------------------------------------------------------------------
__global__ void detect_k(const u32* __restrict__ raw, int* __restrict__ flag) {
  __shared__ int cnt;
  if (threadIdx.x == 0) cnt = 0;
  __syncthreads();
  u32 w = raw[threadIdx.x];
  u32 lo = w & 0xFFFFu;
  int e = (int)((lo >> 7) & 0xFF);
  int pl = (lo == 0u || (e >= 0x70 && e <= 0x8E)) ? 1 : 0;
  atomicAdd(&cnt, pl);
  __syncthreads();
  if (threadIdx.x == 0) *flag = (cnt >= 192) ? 1 : 0;   // 1 = bf16 device data
}

// ------------------------------------------------------------------
// normalize ALL float params -> f32 mirror allf (validated r6/r7)
// ------------------------------------------------------------------
#define NF_NSEG 28
#define NF_TOT  1748007
struct NormFArgs { const void* src[NF_NSEG]; const int* flag; float* dst; };

__global__ __launch_bounds__(256) void norm_f32(NormFArgs a) {
  const int P[NF_NSEG + 1] = {
    0,360000,720000,1080000,1440000,1441200,1442400,1443600,
    1444800,1474800,1504800,1505100,1505400,1535400,1565400,1565700,
    1566000,1626000,1626100,1656100,1686100,1716100,1746100,1746400,
    1746700,1747000,1747300,1748000,1748007};
  int fl = *a.flag;
  int stride = gridDim.x * 256;
  for (int i = blockIdx.x * 256 + threadIdx.x; i < NF_TOT; i += stride) {
    int s = 0;
    while (i >= P[s + 1]) ++s;
    int k = i - P[s];
    float v = fl ? u2f(((const u16*)a.src[s])[k]) : ((const float*)a.src[s])[k];
    a.dst[i] = v;
  }
}
#define AF_LWIH_F 0
#define AF_LWHH_F 360000
#define AF_LWIH_B 720000
#define AF_LWHH_B 1080000
#define AF_LBIH_F 1440000
#define AF_LBHH_F 1441200
#define AF_LBIH_B 1442400
#define AF_LBHH_B 1443600
#define AF_GWIH_F 1444800
#define AF_GWHH_F 1474800
#define AF_GBIH_F 1504800
#define AF_GBHH_F 1505100
#define AF_GWIH_B 1505400
#define AF_GWHH_B 1535400
#define AF_GBIH_B 1565400
#define AF_GBHH_B 1565700
#define AF_LIN1W  1566000
#define AF_LIN1B  1626000
#define AF_ATTWR  1626100
#define AF_ATTUR  1656100
#define AF_ATTW   1686100
#define AF_ATTU   1716100
#define AF_ATTBR  1746100
#define AF_ATTBUR 1746400
#define AF_ATTBW  1746700
#define AF_ATTBU  1747000
#define AF_CLSW   1747300
#define AF_CLSB   1748000

// ------------------------------------------------------------------
// transpose 100x100 chunks to k-major: gWhh (2x3) + att Ur/U (3 hops x2)
// ------------------------------------------------------------------
__global__ void transp_k(const float* __restrict__ allf, float* __restrict__ wt) {
  int idx = blockIdx.x * 256 + threadIdx.x;
  if (idx >= 120000) return;
  int seg = idx / 10000;
  int rem = idx - seg * 10000;
  int k = rem / 100, j = rem - (rem / 100) * 100;
  int srcbase;
  if (seg < 3)      srcbase = AF_GWHH_F + seg * 10000;
  else if (seg < 6) srcbase = AF_GWHH_B + (seg - 3) * 10000;
  else if (seg < 9) srcbase = AF_ATTUR + (seg - 6) * 10000;
  else              srcbase = AF_ATTU  + (seg - 9) * 10000;
  wt[seg * 10000 + k * 100 + j] = allf[srcbase + j * 100 + k];
}

// ------------------------------------------------------------------
// LSTM weights -> wL2[dir][c=j*4+g][k'=0..639] bf16 (K padded 2x320)
// Plus bias sums bsum[dir][g*300+j].
// ------------------------------------------------------------------
__global__ void tr_lstm2(const float* __restrict__ allf, u16* __restrict__ wL2,
                         float* __restrict__ bsum) {
  int idx = blockIdx.x * 256 + threadIdx.x;
  if (idx < 1536000) {
    int dir = idx / 768000;
    int rem = idx - dir * 768000;
    int c = rem / 640, kp = rem - (rem / 640) * 640;
    int j = c >> 2, g = c & 3;
    float v = 0.f;
    if (kp < 320) {
      if (kp < 300)
        v = allf[(dir ? AF_LWIH_B : AF_LWIH_F) + (g * 300 + j) * 300 + kp];
    } else {
      int k2 = kp - 320;
      if (k2 < 300)
        v = allf[(dir ? AF_LWHH_B : AF_LWHH_F) + (g * 300 + j) * 300 + k2];
    }
    wL2[idx] = f2u(v);
  } else if (idx < 1538400) {
    int i2 = idx - 1536000;
    int dir = i2 / 1200, gj = i2 - (i2 / 1200) * 1200;
    bsum[i2] = allf[(dir ? AF_LBIH_B : AF_LBIH_F) + gj]
             + allf[(dir ? AF_LBHH_B : AF_LBHH_F) + gj];
  }
}

// ------------------------------------------------------------------
// gather emb row-major bf16: xallR[t][r][320] (pad 300..319 = 0)
// ------------------------------------------------------------------
__global__ __launch_bounds__(256) void xgat2(const int* __restrict__ sents,
                                             const void* __restrict__ emb,
                                             const int* __restrict__ flag,
                                             u16* __restrict__ xallR) {
  __shared__ int toks[64];
  int tid = threadIdx.x;
  int r0 = blockIdx.x * 64, t = blockIdx.y;
  int fl = *flag;
  if (tid < 64) toks[tid] = sents[(r0 + tid) * S_LEN + t];
  __syncthreads();
  for (int idx = tid; idx < 64 * 320; idx += 256) {
    int r = idx / 320, k = idx - (idx / 320) * 320;
    u16 v = 0;
    if (k < 300) {
      size_t si = (size_t)toks[r] * 300 + k;
      v = fl ? ((const u16*)emb)[si] : f2u(((const float*)emb)[si]);
    }
    xallR[((size_t)t * 512 + r0 + r) * 320 + k] = v;
  }
}

// ------------------------------------------------------------------
// LSTM persistent MFMA scan v10: grid (8 rowT[64], 15 colT[80], 2 dir)
// = 240 blocks (1/CU, 124KB LDS), 512 thr = 8 waves.
// Wave = (rf=w&3 row-frag of 16 rows, ch=w>>2): ch0 owns col-frags 0-2,
// ch1 owns col-frags 3-4; FULL K per wave (x seg bf16 + h seg f32->bf16).
// Single Gs write phase (stride 85, conflict-free), one block barrier.
// Barrier is per-(dir,rowtile) group of 15 blocks (localized: block only
// needs h of its own 64 rows, produced by its group) -> groups pipeline
// independently. MFMA convention == r2/r3 bit-identical-validated.
// ------------------------------------------------------------------
struct Lstm10Args {
  const int* lens;
  const u16* xallR;     // [100][512][320] bf16
  const u16* wL2;       // [dir][1200][640] bf16
  const float* bsum;    // [dir][1200] (g*300+j)
  float* hbufR;         // [2 par][2 dir][512][320] f32 (pad j>=300 stays 0)
  float* maxb;          // [512][600]
  int* cnt;             // per-group: ctr at gi*64, flag at gi*64+16
};

__global__ __launch_bounds__(512, 1) void lstm10(Lstm10Args a) {
  __shared__ u16   WLh[80 * 640];    // 102400 B, swizzled: byte^=((cc&7)<<4)
  __shared__ float Gs[64 * 85];      // 21760 B
  const int tid = threadIdx.x;
  const int r0  = blockIdx.x * 64;
  const int ct  = blockIdx.y;        // j0 = ct*20
  const int dir = blockIdx.z;

  // ---- stage W slice once
  {
    const u64* wsrc = (const u64*)(a.wL2 + (size_t)dir * 768000 + (size_t)ct * 80 * 640);
    for (int i = tid; i < 80 * 160; i += 512) {
      int cc = i / 160, kw = i - (i / 160) * 160;
      u64 v = wsrc[(size_t)cc * 160 + kw];
      *(u64*)((char*)WLh + cc * 1280 + ((kw * 8) ^ ((cc & 7) << 4))) = v;
    }
  }

  const int w  = tid >> 6;
  const int rf = w & 3;              // row-frag (16 rows)
  const int ch = w >> 2;             // col-half: 0 -> cf 0..2, 1 -> cf 3..4
  const int cf0 = ch ? 3 : 0;
  const int ncf = ch ? 2 : 3;
  const int l  = tid & 63;
  const int lr = l & 15;
  const int aq = l >> 4;
  const int arow = r0 + rf * 16 + lr;

  // ---- per-thread cells: up to 3 of (64 rows x 20 j), idx = tid + i*512
  float cq[3] = {0.f, 0.f, 0.f}, hq[3] = {0.f, 0.f, 0.f};
  float mxv[3] = {-INFINITY, -INFINITY, -INFINITY};
  float bsv[3][4];
  int lenv[3];
  #pragma unroll
  for (int i = 0; i < 3; ++i) {
    int idx = tid + i * 512;
    if (idx < 1280) {
      int r = idx / 20, jj = idx - (idx / 20) * 20;
      int j = ct * 20 + jj;
      lenv[i] = a.lens[r0 + r];
      #pragma unroll
      for (int g = 0; g < 4; ++g) bsv[i][g] = a.bsum[dir * 1200 + g * 300 + j];
    } else {
      lenv[i] = 0;
      bsv[i][0] = bsv[i][1] = bsv[i][2] = bsv[i][3] = 0.f;
    }
  }

  const int gi = dir * 8 + blockIdx.x;       // barrier group id (16 groups)
  int* cptr = a.cnt + gi * 64;
  int* fptr = a.cnt + gi * 64 + 16;
  __syncthreads();

  for (int s = 0; s < S_LEN; ++s) {
    const int tt  = dir ? (S_LEN - 1 - s) : s;
    const int cur = s & 1, nxt = cur ^ 1;

    f32x4 acc[3];
    #pragma unroll
    for (int i = 0; i < 3; ++i) acc[i] = (f32x4){0, 0, 0, 0};

    // ---- x segment: ks 0..9, A = bf16 direct, prefetch 1-deep
    {
      const u16* xrow = a.xallR + ((size_t)tt * 512 + arow) * 320 + aq * 8;
      bf16x8 Af = *(const bf16x8*)(xrow);
      #pragma unroll
      for (int ks = 0; ks < 10; ++ks) {
        bf16x8 An = (ks < 9) ? *(const bf16x8*)(xrow + (ks + 1) * 32) : Af;
        #pragma unroll
        for (int i = 0; i < 3; ++i) {
          if (i < ncf) {
            int cc = (cf0 + i) * 16 + lr;
            bf16x8 Bf = *(const bf16x8*)((const char*)WLh + cc * 1280 +
                                         ((ks * 64 + aq * 16) ^ ((cc & 7) << 4)));
            acc[i] = __builtin_amdgcn_mfma_f32_16x16x32_bf16(Af, Bf, acc[i], 0, 0, 0);
          }
        }
        Af = An;
      }
    }
    // ---- h segment: ks 10..19, A = f32 -> bf16 pack, prefetch 1-deep
    {
      const float* hrow = a.hbufR + (((size_t)cur * 2 + dir) * 512 + arow) * 320 + aq * 8;
      float4 h0 = *(const float4*)hrow;
      float4 h1 = *(const float4*)(hrow + 4);
      #pragma unroll
      for (int ks = 0; ks < 10; ++ks) {
        float4 n0, n1;
        if (ks < 9) {
          n0 = *(const float4*)(hrow + (ks + 1) * 32);
          n1 = *(const float4*)(hrow + (ks + 1) * 32 + 4);
        }
        union { u32 u[4]; bf16x8 v; } pk;
        pk.u[0] = ((u32)f2u(h0.y) << 16) | (u32)f2u(h0.x);
        pk.u[1] = ((u32)f2u(h0.w) << 16) | (u32)f2u(h0.z);
        pk.u[2] = ((u32)f2u(h1.y) << 16) | (u32)f2u(h1.x);
        pk.u[3] = ((u32)f2u(h1.w) << 16) | (u32)f2u(h1.z);
        bf16x8 Af = pk.v;
        #pragma unroll
        for (int i = 0; i < 3; ++i) {
          if (i < ncf) {
            int cc = (cf0 + i) * 16 + lr;
            bf16x8 Bf = *(const bf16x8*)((const char*)WLh + cc * 1280 +
                                         (((ks + 10) * 64 + aq * 16) ^ ((cc & 7) << 4)));
            acc[i] = __builtin_amdgcn_mfma_f32_16x16x32_bf16(Af, Bf, acc[i], 0, 0, 0);
          }
        }
        if (ks < 9) { h0 = n0; h1 = n1; }
      }
    }

    // ---- gate exchange: single write phase (C row=(l>>4)*4+reg, col=l&15)
    #pragma unroll
    for (int rr = 0; rr < 4; ++rr) {
      int gr = (rf * 16 + aq * 4 + rr) * 85;
      #pragma unroll
      for (int i = 0; i < 3; ++i) {
        if (i < ncf) Gs[gr + (cf0 + i) * 16 + lr] = acc[i][rr];
      }
    }
    __syncthreads();

    // ---- cell update (gate order i,f,g,o at cols jj*4+g)
    #pragma unroll
    for (int i = 0; i < 3; ++i) {
      int idx = tid + i * 512;
      if (idx < 1280) {
        int r = idx / 20, jj = idx - (idx / 20) * 20;
        bool m = tt < lenv[i];
        if (m) {
          float gi_ = Gs[r * 85 + jj * 4 + 0] + bsv[i][0];
          float gf  = Gs[r * 85 + jj * 4 + 1] + bsv[i][1];
          float gg  = Gs[r * 85 + jj * 4 + 2] + bsv[i][2];
          float go  = Gs[r * 85 + jj * 4 + 3] + bsv[i][3];
          cq[i] = sigm(gf) * cq[i] + sigm(gi_) * tanhf(gg);
          hq[i] = sigm(go) * tanhf(cq[i]);
          mxv[i] = fmaxf(mxv[i], hq[i]);
        } else {
          mxv[i] = fmaxf(mxv[i], 0.f);
        }
        a.hbufR[(((size_t)nxt * 2 + dir) * 512 + r0 + r) * 320 + ct * 20 + jj] = hq[i];
      }
    }

    // ---- per-(dir,rowtile) group barrier: 15 arrivals, epoch flag
    __syncthreads();
    if (tid == 0) {
      __threadfence();
      int old = __hip_atomic_fetch_add(cptr, 1, __ATOMIC_ACQ_REL, __HIP_MEMORY_SCOPE_AGENT);
      if (old == GRPSZ * (s + 1) - 1) {
        __hip_atomic_store(fptr, s + 1, __ATOMIC_RELEASE, __HIP_MEMORY_SCOPE_AGENT);
      } else {
        while (__hip_atomic_load(fptr, __ATOMIC_ACQUIRE, __HIP_MEMORY_SCOPE_AGENT) < s + 1)
          __builtin_amdgcn_s_sleep(1);
      }
      __threadfence();
    }
    __syncthreads();
  }

  // ---- maxpool writeout
  #pragma unroll
  for (int i = 0; i < 3; ++i) {
    int idx = tid + i * 512;
    if (idx < 1280) {
      int r = idx / 20, jj = idx - (idx / 20) * 20;
      a.maxb[(size_t)(r0 + r) * 600 + dir * 300 + ct * 20 + jj] = mxv[i];
    }
  }
}

// ------------------------------------------------------------------
// s_utt = tanh(maxpl @ lin1_W^T + lin1_b)   [512,100]
// ------------------------------------------------------------------
__global__ __launch_bounds__(128) void sutt_k(const float* __restrict__ maxb,
                                              const float* __restrict__ W,
                                              const float* __restrict__ bb,
                                              float* __restrict__ sutt) {
  int b = blockIdx.x, tid = threadIdx.x;
  __shared__ float mx[600];
  for (int i = tid; i < 600; i += 128) mx[i] = maxb[b * 600 + i];
  __syncthreads();
  if (tid < 100) {
    float acc = bb[tid];
    const float* wr = W + tid * 600;
    for (int k = 0; k < 600; ++k) acc += mx[k] * wr[k];
    sutt[b * 100 + tid] = tanhf(acc);
  }
}

// ------------------------------------------------------------------
// GRU x-projection: xg[dir][t][row][300] f32 (incl. bih)
// ------------------------------------------------------------------
__global__ __launch_bounds__(256) void gxg3(const float* __restrict__ sutt,
                                            const float* __restrict__ Wf, const float* __restrict__ bf_,
                                            const float* __restrict__ Wb, const float* __restrict__ bb_,
                                            float* __restrict__ xg) {
  __shared__ float bts[32][101];
  int tid = threadIdx.x;
  int rt = blockIdx.x * 32, t = blockIdx.y, dir = blockIdx.z;
  int tin = dir ? (39 - t) : t;
  for (int idx = tid; idx < 3200; idx += 256) {
    int r = idx / 100, k = idx - r * 100, row = rt + r;
    float v = 0.f;
    if (row < BM1) {
      int srow = row + 1 - 40 + tin;
      if (srow >= 0) v = sutt[srow * 100 + k];
    }
    bts[r][k] = v;
  }
  __syncthreads();
  const float* Wm = dir ? Wb : Wf;
  const float* bm = dir ? bb_ : bf_;
  for (int o = tid; o < 9600; o += 256) {
    int r = o & 31, g = o >> 5;
    float acc = bm[g];
    const float* wr = Wm + g * 100;
    const float* br = bts[r];
    for (int k = 0; k < 100; ++k) acc += br[k] * wr[k];
    int row = rt + r;
    if (row < BM1) xg[(((size_t)dir * 40 + t) * BM1 + row) * 300 + g] = acc;
  }
}

// ------------------------------------------------------------------
// GRU scan v4 (validated r9)
// ------------------------------------------------------------------
struct Gru4Args {
  const float* wt;
  const float* bhh[2];
  const float* xg;
  float* memf; float* memb;
};

__global__ __launch_bounds__(512) void gru4(Gru4Args a) {
  __shared__ float WT[30000];
  __shared__ float hl[2][4][104];
  int tid = threadIdx.x, rt = blockIdx.x * 4, dir = blockIdx.y;
  const float* src = a.wt + dir * 30000;
  for (int i = tid; i < 30000; i += 512) WT[i] = src[i];
  for (int i = tid; i < 832; i += 512) ((float*)hl)[i] = 0.f;
  int r = tid / 100, j = tid - r * 100;
  int row = rt + r;
  bool act = (tid < 400) && (row < BM1);
  const float* bhh = a.bhh[dir];
  float xr = 0.f, xz = 0.f, xn = 0.f;
  if (act) {
    size_t xb = ((size_t)(dir * 40) * BM1 + row) * 300;
    xr = a.xg[xb + j]; xz = a.xg[xb + 100 + j]; xn = a.xg[xb + 200 + j];
  }
  float hprev = 0.f;
  __syncthreads();
  for (int t = 0; t < 40; ++t) {
    int nxt = (t + 1) & 1, cur = t & 1;
    float xr2 = 0.f, xz2 = 0.f, xn2 = 0.f;
    if (act && t < 39) {
      size_t xb = ((size_t)(dir * 40 + t + 1) * BM1 + row) * 300;
      xr2 = a.xg[xb + j]; xz2 = a.xg[xb + 100 + j]; xn2 = a.xg[xb + 200 + j];
    }
    float v = 0.f;
    if (act) {
      float hr = bhh[j], hz = bhh[100 + j], hn = bhh[200 + j];
      const float* w0 = WT + j;
      const float* hrow = hl[cur][r];
      for (int k = 0; k < 100; ++k) {
        float hv = hrow[k];
        hr += hv * w0[k * 100];
        hz += hv * w0[10000 + k * 100];
        hn += hv * w0[20000 + k * 100];
      }
      float rg_ = sigm(xr + hr), zg = sigm(xz + hz);
      float ng = tanhf(xn + rg_ * hn);
      v = (1.f - zg) * ng + zg * hprev;
      int tin = dir ? (39 - t) : t;
      (dir ? a.memb : a.memf)[((size_t)tin * BM1 + row) * 100 + j] = v;
    }
    if (tid < 400) hl[nxt][r][j] = v;
    hprev = v;
    __syncthreads();
    xr = xr2; xz = xz2; xn = xn2;
  }
}

// mem = bt + mem_f + mem_b
__global__ void memcomb(const float* __restrict__ memf, const float* __restrict__ memb,
                        const float* __restrict__ sutt, float* __restrict__ memm) {
  int idx = blockIdx.x * 256 + threadIdx.x;
  if (idx >= 40 * BM1 * 100) return;
  int j = idx % 100; int rem = idx / 100; int row = rem % BM1; int t = rem / BM1;
  float v = memf[idx] + memb[idx];
  int sidx = row + 1 - 40 + t;
  if (sidx >= 0) v += sutt[sidx * 100 + j];
  memm[idx] = v;
}

__global__ void epsinit(const float* __restrict__ sutt, float* __restrict__ eps) {
  int idx = blockIdx.x * 256 + threadIdx.x;
  if (idx < BM1 * 100) eps[idx] = sutt[idx + 100];
}

// attention scores + softmax -> gates + attn output (f32)
__global__ __launch_bounds__(64) void attnsc(const float* __restrict__ eps,
                                             const float* __restrict__ memm,
                                             float* __restrict__ gatesw,
                                             float* __restrict__ outat) {
  int row = blockIdx.x, k = threadIdx.x;
  __shared__ float el[100];
  for (int i = k; i < 100; i += 64) el[i] = eps[row * 100 + i];
  __syncthreads();
  float val = -INFINITY;
  if (k < 40) {
    if (row + 1 - 40 + k >= 0) {
      const float* mrow = memm + ((size_t)k * BM1 + row) * 100;
      float s = 0.f;
      for (int d = 0; d < 100; ++d) s += el[d] * mrow[d];
      val = s;
    } else val = -1e10f;
  }
  float mx = val;
  for (int off = 32; off > 0; off >>= 1) mx = fmaxf(mx, __shfl_xor(mx, off));
  float ex = (k < 40) ? expf(val - mx) : 0.f;
  float sm = ex;
  for (int off = 32; off > 0; off >>= 1) sm += __shfl_xor(sm, off);
  if (k < 40) {
    float sc = ex / sm;
    gatesw[k * BM1 + row] = sc;
    outat[row * 40 + k] = sc;
  }
}

// cr/cw precompute GEMM: grid (16, 40, 2)
__global__ __launch_bounds__(256) void crcw3(const float* __restrict__ memm,
                                             const float* __restrict__ Wr, const float* __restrict__ br,
                                             const float* __restrict__ Ww, const float* __restrict__ bw,
                                             float* __restrict__ crb, float* __restrict__ cwb) {
  __shared__ float ml[32][101];
  int tid = threadIdx.x;
  int rt = blockIdx.x * 32, t = blockIdx.y, which = blockIdx.z;
  for (int idx = tid; idx < 3200; idx += 256) {
    int r = idx / 100, k = idx - r * 100; int row = rt + r;
    ml[r][k] = (row < BM1) ? memm[((size_t)t * BM1 + row) * 100 + k] : 0.f;
  }
  __syncthreads();
  const float* Wm = which ? Ww : Wr;
  const float* bm = which ? bw : br;
  float* ob = which ? cwb : crb;
  for (int o = tid; o < 3200; o += 256) {
    int r = o & 31, hh = o >> 5;
    float acc = bm[hh];
    const float* wr = Wm + hh * 100;
    for (int k = 0; k < 100; ++k) acc += ml[r][k] * wr[k];
    int row = rt + r;
    if (row < BM1) ob[((size_t)t * BM1 + row) * 100 + hh] = acc;
  }
}

// ------------------------------------------------------------------
// AttnGRU scan v4 (validated r9)
// ------------------------------------------------------------------
struct Att4Args {
  const float* urT; const float* uT;
  const float* bur; const float* bu;
  const float* crb; const float* cwb;
  const float* gatesw; float* eps;
};

__global__ __launch_bounds__(512) void attscan4(Att4Args a) {
  __shared__ float UrT[10000];
  __shared__ float UT[10000];
  __shared__ float hl[2][4][104];
  int tid = threadIdx.x, rt = blockIdx.x * 4;
  for (int i = tid; i < 10000; i += 512) { UrT[i] = a.urT[i]; UT[i] = a.uT[i]; }
  for (int i = tid; i < 832; i += 512) ((float*)hl)[i] = 0.f;
  int r = tid / 100, j = tid - r * 100;
  int row = rt + r;
  bool act = (tid < 400) && (row < BM1);
  float cr = 0.f, cw = 0.f, gw = 0.f;
  if (act) {
    size_t ix = (size_t)row * 100 + j;
    cr = a.crb[ix]; cw = a.cwb[ix]; gw = a.gatesw[row];
  }
  float hprev = 0.f;
  __syncthreads();
  for (int t = 0; t < 40; ++t) {
    int nxt = (t + 1) & 1, cur = t & 1;
    float cr2 = 0.f, cw2 = 0.f, gw2 = 0.f;
    if (act && t < 39) {
      size_t ix = ((size_t)(t + 1) * BM1 + row) * 100 + j;
      cr2 = a.crb[ix]; cw2 = a.cwb[ix]; gw2 = a.gatesw[(t + 1) * BM1 + row];
    }
    float v = 0.f;
    if (act) {
      float hr = a.bur[j], hu = a.bu[j];
      const float* hrow = hl[cur][r];
      for (int k = 0; k < 100; ++k) {
        float hv = hrow[k];
        hr += hv * UrT[k * 100 + j];
        hu += hv * UT[k * 100 + j];
      }
      float rg_ = sigm(cr + hr);
      float ht = tanhf(cw + rg_ * hu);
      v = gw * ht + (1.f - gw) * hprev;
    }
    if (tid < 400) hl[nxt][r][j] = v;
    hprev = v;
    __syncthreads();
    cr = cr2; cw = cw2; gw = gw2;
  }
  if (act) a.eps[(size_t)row * 100 + j] += hprev;
}

// classifier -> f32
__global__ __launch_bounds__(64) void cls_k(const float* __restrict__ sutt,
                                            const float* __restrict__ eps,
                                            const float* __restrict__ cW, const float* __restrict__ cb,
                                            float* __restrict__ outp) {
  int b = blockIdx.x, j = threadIdx.x;
  __shared__ float sl[100];
  for (int i = j; i < 100; i += 64) sl[i] = (b == 0) ? sutt[i] : eps[(b - 1) * 100 + i];
  __syncthreads();
  float lg = -INFINITY;
  if (j < 7) {
    lg = cb[j];
    const float* wr = cW + j * 100;
    for (int k = 0; k < 100; ++k) lg += sl[k] * wr[k];
  }
  float mx = lg;
  for (int off = 32; off > 0; off >>= 1) mx = fmaxf(mx, __shfl_xor(mx, off));
  float ex = (j < 7) ? expf(lg - mx) : 0.f;
  float sm = ex;
  for (int off = 32; off > 0; off >>= 1) sm += __shfl_xor(sm, off);
  if (j < 7) outp[b * 7 + j] = lg - mx - logf(sm);
}

// ------------------------------------------------------------------
extern "C" void kernel_launch(void* const* d_in, const int* in_sizes, int n_in,
                              void* d_out, int out_size, void* d_ws, size_t ws_size,
                              hipStream_t stream) {
  (void)n_in; (void)out_size; (void)ws_size;

  bool sigOrder = (in_sizes[7] == 360000);   // r4 evidence: dict order

  const void *p_sents, *p_lens, *p_emb;
  const void *p_lWih_f, *p_lWhh_f, *p_lbih_f, *p_lbhh_f;
  const void *p_lWih_b, *p_lWhh_b, *p_lbih_b, *p_lbhh_b;
  const void *p_gWih_f, *p_gWhh_f, *p_gbih_f, *p_gbhh_f;
  const void *p_gWih_b, *p_gWhh_b, *p_gbih_b, *p_gbhh_b;
  const void *p_lin1W, *p_lin1b;
  const void *p_attWr, *p_attUr, *p_attW, *p_attU;
  const void *p_attbr, *p_attbur, *p_attbw, *p_attbu;
  const void *p_clsW, *p_clsb;

  p_sents = d_in[0]; p_lens = d_in[1]; p_emb = d_in[2];
  p_lWih_f = d_in[3]; p_lWhh_f = d_in[4]; p_lbih_f = d_in[5]; p_lbhh_f = d_in[6];
  if (sigOrder) {
    p_lWih_b = d_in[7];  p_lWhh_b = d_in[8];  p_lbih_b = d_in[9];  p_lbhh_b = d_in[10];
    p_lin1W  = d_in[11]; p_lin1b  = d_in[12];
    p_gWih_f = d_in[13]; p_gWhh_f = d_in[14]; p_gbih_f = d_in[15]; p_gbhh_f = d_in[16];
    p_gWih_b = d_in[17]; p_gWhh_b = d_in[18]; p_gbih_b = d_in[19]; p_gbhh_b = d_in[20];
    p_attWr  = d_in[21]; p_attbr  = d_in[22]; p_attUr  = d_in[23]; p_attbur = d_in[24];
    p_attW   = d_in[25]; p_attbw  = d_in[26]; p_attU   = d_in[27]; p_attbu  = d_in[28];
    p_clsW   = d_in[29]; p_clsb   = d_in[30];
  } else {
    p_gWih_f = d_in[7];  p_gWhh_f = d_in[8];  p_gbih_f = d_in[9];  p_gbhh_f = d_in[10];
    p_lWih_b = d_in[11]; p_lWhh_b = d_in[12]; p_lbih_b = d_in[13]; p_lbhh_b = d_in[14];
    p_gWih_b = d_in[15]; p_gWhh_b = d_in[16]; p_gbih_b = d_in[17]; p_gbhh_b = d_in[18];
    p_lin1W  = d_in[19]; p_lin1b  = d_in[20];
    p_attWr  = d_in[21]; p_attUr  = d_in[22]; p_attW   = d_in[23]; p_attU   = d_in[24];
    p_attbr  = d_in[25]; p_attbur = d_in[26]; p_attbw  = d_in[27]; p_attbu  = d_in[28];
    p_clsW   = d_in[29]; p_clsb   = d_in[30];
  }

  char* wp = (char*)d_ws;
  auto carve = [&](size_t bytes) {
    char* p = wp;
    wp += (bytes + 255) & ~(size_t)255;
    return p;
  };
  int*   flag  = (int*)  carve(256);
  int*   cnt   = (int*)  carve(4096);
  float* allf  = (float*)carve((size_t)NF_TOT * 4);
  float* wt    = (float*)carve((size_t)120000 * 4);
  u16*   wL2   = (u16*)  carve((size_t)1536000 * 2);
  float* bsum  = (float*)carve((size_t)2400 * 4);
  float* hbufR = (float*)carve((size_t)2 * 2 * 512 * 320 * 4);
  float* maxb  = (float*)carve((size_t)B_SZ * 600 * 4);
  float* sutt  = (float*)carve((size_t)B_SZ * 100 * 4);
  // big region: xallR (bf16, dead after lstm10) aliases xg+memf+memb
  size_t xg_sz   = (size_t)2 * 40 * BM1 * 300 * 4;
  size_t memf_sz = (size_t)40 * BM1 * 100 * 4;
  char*  big   = carve(xg_sz + 2 * memf_sz);
  u16*   xallR = (u16*)big;
  float* xg    = (float*)big;
  float* memf  = (float*)(big + xg_sz);
  float* memb  = (float*)(big + xg_sz + memf_sz);
  float* memm  = (float*)carve(memf_sz);
  float* gatesw= (float*)carve((size_t)40 * BM1 * 4);
  float* eps   = (float*)carve((size_t)BM1 * 100 * 4);
  float* crb   = xg;
  float* cwb   = xg + (size_t)40 * BM1 * 100;

  float* out_pred = (float*)d_out;
  float* out_attn = out_pred + (size_t)B_SZ * NC_;

  detect_k<<<1, 256, 0, stream>>>((const u32*)p_emb, flag);

  NormFArgs nf;
  {
    const void* srcs[NF_NSEG] = {
      p_lWih_f, p_lWhh_f, p_lWih_b, p_lWhh_b,
      p_lbih_f, p_lbhh_f, p_lbih_b, p_lbhh_b,
      p_gWih_f, p_gWhh_f, p_gbih_f, p_gbhh_f,
      p_gWih_b, p_gWhh_b, p_gbih_b, p_gbhh_b,
      p_lin1W,  p_lin1b,
      p_attWr,  p_attUr,  p_attW,   p_attU,
      p_attbr,  p_attbur, p_attbw,  p_attbu,
      p_clsW,   p_clsb };
    for (int i = 0; i < NF_NSEG; ++i) nf.src[i] = srcs[i];
    nf.flag = flag; nf.dst = allf;
  }
  norm_f32<<<2048, 256, 0, stream>>>(nf);
  transp_k<<<(120000 + 255) / 256, 256, 0, stream>>>(allf, wt);
  tr_lstm2<<<(1538400 + 255) / 256, 256, 0, stream>>>(allf, wL2, bsum);
  xgat2<<<dim3(8, 100), 256, 0, stream>>>((const int*)p_sents, p_emb, flag, xallR);

  hipMemsetAsync(cnt, 0, 4096, stream);
  hipMemsetAsync(hbufR, 0, (size_t)2 * 2 * 512 * 320 * 4, stream);

  Lstm10Args la;
  la.lens = (const int*)p_lens;
  la.xallR = xallR; la.wL2 = wL2; la.bsum = bsum;
  la.hbufR = hbufR; la.maxb = maxb; la.cnt = cnt;
  lstm10<<<dim3(8, 15, 2), 512, 0, stream>>>(la);

  sutt_k<<<512, 128, 0, stream>>>(maxb, allf + AF_LIN1W, allf + AF_LIN1B, sutt);

  gxg3<<<dim3(16, 40, 2), 256, 0, stream>>>(sutt,
      allf + AF_GWIH_F, allf + AF_GBIH_F,
      allf + AF_GWIH_B, allf + AF_GBIH_B, xg);

  Gru4Args ga;
  ga.wt = wt;
  ga.bhh[0] = allf + AF_GBHH_F; ga.bhh[1] = allf + AF_GBHH_B;
  ga.xg = xg; ga.memf = memf; ga.memb = memb;
  gru4<<<dim3(128, 2), 512, 0, stream>>>(ga);

  memcomb<<<(40 * BM1 * 100 + 255) / 256, 256, 0, stream>>>(memf, memb, sutt, memm);
  epsinit<<<(BM1 * 100 + 255) / 256, 256, 0, stream>>>(sutt, eps);

  for (int hop = 0; hop < NHOP; ++hop) {
    attnsc<<<BM1, 64, 0, stream>>>(eps, memm, gatesw, out_attn + (size_t)hop * BM1 * 40);
    crcw3<<<dim3(16, 40, 2), 256, 0, stream>>>(memm,
        allf + AF_ATTWR + hop * 10000, allf + AF_ATTBR + hop * 100,
        allf + AF_ATTW  + hop * 10000, allf + AF_ATTBW + hop * 100, crb, cwb);
    Att4Args aa;
    aa.urT = wt + 60000 + hop * 10000;
    aa.uT  = wt + 90000 + hop * 10000;
    aa.bur = allf + AF_ATTBUR + hop * 100;
    aa.bu  = allf + AF_ATTBU  + hop * 100;
    aa.crb = crb; aa.cwb = cwb;
    aa.gatesw = gatesw; aa.eps = eps;
    attscan4<<<128, 512, 0, stream>>>(aa);
  }

  cls_k<<<512, 64, 0, stream>>>(sutt, eps, allf + AF_CLSW, allf + AF_CLSB, out_pred);
}

// Round 16
// 3557.698 us; speedup vs baseline: 1.1077x; 1.0446x over previous
//
#include <hip/hip_runtime.h>
#include <cstdint>
#include <cstddef>

typedef unsigned short u16;
typedef unsigned int   u32;
typedef unsigned long long u64;

#define S_LEN 100
#define B_SZ  512
#define H_LS  300
#define NHOP  3
#define NC_   7
#define BM1   511   // B-1
#define GRPSZ 15    // lstm11 barrier group size (col-tiles per row-tile)

using bf16x8 = __attribute__((ext_vector_type(8))) short;
using f32x4  = __attribute__((ext_vector_type(4))) float;

__device__ __forceinline__ float u2f(u16 u) {
  union { u32 i; float f; } x; x.i = ((u32)u) << 16; return x.f;
}
__device__ __forceinline__ u16 f2u(float f) {
  u32 bits = __float_as_uint(f);
  bits += 0x7fffu + ((bits >> 16) & 1u);   // RNE
  return (u16)(bits >> 16);
}
__device__ __forceinline__ float sigm(float x) { return 1.0f / (1.0f + expf(-x)); }

// ------------------------------------------------------------------
// dtype detect on emb raw bits (validated r1->r2)
// ------------------------------------------------------------------
__global__ void detect_k(const u32* __restrict__ raw, int* __restrict__ flag) {
  __shared__ int cnt;
  if (threadIdx.x == 0) cnt = 0;
  __syncthreads();
  u32 w = raw[threadIdx.x];
  u32 lo = w & 0xFFFFu;
  int e = (int)((lo >> 7) & 0xFF);
  int pl = (lo == 0u || (e >= 0x70 && e <= 0x8E)) ? 1 : 0;
  atomicAdd(&cnt, pl);
  __syncthreads();
  if (threadIdx.x == 0) *flag = (cnt >= 192) ? 1 : 0;   // 1 = bf16 device data
}

// ------------------------------------------------------------------
// normalize ALL float params -> f32 mirror allf (validated r6/r7)
// ------------------------------------------------------------------
#define NF_NSEG 28
#define NF_TOT  1748007
struct NormFArgs { const void* src[NF_NSEG]; const int* flag; float* dst; };

__global__ __launch_bounds__(256) void norm_f32(NormFArgs a) {
  const int P[NF_NSEG + 1] = {
    0,360000,720000,1080000,1440000,1441200,1442400,1443600,
    1444800,1474800,1504800,1505100,1505400,1535400,1565400,1565700,
    1566000,1626000,1626100,1656100,1686100,1716100,1746100,1746400,
    1746700,1747000,1747300,1748000,1748007};
  int fl = *a.flag;
  int stride = gridDim.x * 256;
  for (int i = blockIdx.x * 256 + threadIdx.x; i < NF_TOT; i += stride) {
    int s = 0;
    while (i >= P[s + 1]) ++s;
    int k = i - P[s];
    float v = fl ? u2f(((const u16*)a.src[s])[k]) : ((const float*)a.src[s])[k];
    a.dst[i] = v;
  }
}
#define AF_LWIH_F 0
#define AF_LWHH_F 360000
#define AF_LWIH_B 720000
#define AF_LWHH_B 1080000
#define AF_LBIH_F 1440000
#define AF_LBHH_F 1441200
#define AF_LBIH_B 1442400
#define AF_LBHH_B 1443600
#define AF_GWIH_F 1444800
#define AF_GWHH_F 1474800
#define AF_GBIH_F 1504800
#define AF_GBHH_F 1505100
#define AF_GWIH_B 1505400
#define AF_GWHH_B 1535400
#define AF_GBIH_B 1565400
#define AF_GBHH_B 1565700
#define AF_LIN1W  1566000
#define AF_LIN1B  1626000
#define AF_ATTWR  1626100
#define AF_ATTUR  1656100
#define AF_ATTW   1686100
#define AF_ATTU   1716100
#define AF_ATTBR  1746100
#define AF_ATTBUR 1746400
#define AF_ATTBW  1746700
#define AF_ATTBU  1747000
#define AF_CLSW   1747300
#define AF_CLSB   1748000

// ------------------------------------------------------------------
// transpose 100x100 chunks to k-major: gWhh (2x3) + att Ur/U (3 hops x2)
// ------------------------------------------------------------------
__global__ void transp_k(const float* __restrict__ allf, float* __restrict__ wt) {
  int idx = blockIdx.x * 256 + threadIdx.x;
  if (idx >= 120000) return;
  int seg = idx / 10000;
  int rem = idx - seg * 10000;
  int k = rem / 100, j = rem - (rem / 100) * 100;
  int srcbase;
  if (seg < 3)      srcbase = AF_GWHH_F + seg * 10000;
  else if (seg < 6) srcbase = AF_GWHH_B + (seg - 3) * 10000;
  else if (seg < 9) srcbase = AF_ATTUR + (seg - 6) * 10000;
  else              srcbase = AF_ATTU  + (seg - 9) * 10000;
  wt[seg * 10000 + k * 100 + j] = allf[srcbase + j * 100 + k];
}

// ------------------------------------------------------------------
// LSTM weights -> wL2[dir][c=j*4+g][k'=0..639] bf16 (K padded 2x320)
// Plus bias sums bsum[dir][g*300+j].
// ------------------------------------------------------------------
__global__ void tr_lstm2(const float* __restrict__ allf, u16* __restrict__ wL2,
                         float* __restrict__ bsum) {
  int idx = blockIdx.x * 256 + threadIdx.x;
  if (idx < 1536000) {
    int dir = idx / 768000;
    int rem = idx - dir * 768000;
    int c = rem / 640, kp = rem - (rem / 640) * 640;
    int j = c >> 2, g = c & 3;
    float v = 0.f;
    if (kp < 320) {
      if (kp < 300)
        v = allf[(dir ? AF_LWIH_B : AF_LWIH_F) + (g * 300 + j) * 300 + kp];
    } else {
      int k2 = kp - 320;
      if (k2 < 300)
        v = allf[(dir ? AF_LWHH_B : AF_LWHH_F) + (g * 300 + j) * 300 + k2];
    }
    wL2[idx] = f2u(v);
  } else if (idx < 1538400) {
    int i2 = idx - 1536000;
    int dir = i2 / 1200, gj = i2 - (i2 / 1200) * 1200;
    bsum[i2] = allf[(dir ? AF_LBIH_B : AF_LBIH_F) + gj]
             + allf[(dir ? AF_LBHH_B : AF_LBHH_F) + gj];
  }
}

// ------------------------------------------------------------------
// gather emb row-major bf16: xallR[t][r][320] (pad 300..319 = 0)
// ------------------------------------------------------------------
__global__ __launch_bounds__(256) void xgat2(const int* __restrict__ sents,
                                             const void* __restrict__ emb,
                                             const int* __restrict__ flag,
                                             u16* __restrict__ xallR) {
  __shared__ int toks[64];
  int tid = threadIdx.x;
  int r0 = blockIdx.x * 64, t = blockIdx.y;
  int fl = *flag;
  if (tid < 64) toks[tid] = sents[(r0 + tid) * S_LEN + t];
  __syncthreads();
  for (int idx = tid; idx < 64 * 320; idx += 256) {
    int r = idx / 320, k = idx - (idx / 320) * 320;
    u16 v = 0;
    if (k < 300) {
      size_t si = (size_t)toks[r] * 300 + k;
      v = fl ? ((const u16*)emb)[si] : f2u(((const float*)emb)[si]);
    }
    xallR[((size_t)t * 512 + r0 + r) * 320 + k] = v;
  }
}

// ------------------------------------------------------------------
// LSTM persistent MFMA scan v11 (= v10 + bf16 h exchange + early h-load):
// grid (8 rowT[64], 15 colT[80], 2 dir) = 240 blocks (1/CU), 512 thr.
// Wave = (rf=w&3 row-frag, ch=w>>2 col-half: ch0 cf 0-2, ch1 cf 3-4),
// FULL K per wave. h exchanged as bf16 (halves fence-flush traffic;
// numerically identical: MFMA consumed f2u(h) already). All 10 h-frag
// loads issued right after the barrier so HBM latency hides under the
// x-segment MFMAs. Per-(dir,rowtile) group barrier (15 arrivals).
// MFMA convention == r2/r3 bit-identical-validated.
// ------------------------------------------------------------------
struct Lstm11Args {
  const int* lens;
  const u16* xallR;     // [100][512][320] bf16
  const u16* wL2;       // [dir][1200][640] bf16
  const float* bsum;    // [dir][1200] (g*300+j)
  u16* hbufH;           // [2 par][2 dir][512][320] bf16 (pad j>=300 stays 0)
  float* maxb;          // [512][600]
  int* cnt;             // per-group: ctr at gi*64, flag at gi*64+16
};

__global__ __launch_bounds__(512, 1) void lstm11(Lstm11Args a) {
  __shared__ u16   WLh[80 * 640];    // 102400 B, swizzled: byte^=((cc&7)<<4)
  __shared__ float Gs[64 * 85];      // 21760 B
  const int tid = threadIdx.x;
  const int r0  = blockIdx.x * 64;
  const int ct  = blockIdx.y;        // j0 = ct*20
  const int dir = blockIdx.z;

  // ---- stage W slice once
  {
    const u64* wsrc = (const u64*)(a.wL2 + (size_t)dir * 768000 + (size_t)ct * 80 * 640);
    for (int i = tid; i < 80 * 160; i += 512) {
      int cc = i / 160, kw = i - (i / 160) * 160;
      u64 v = wsrc[(size_t)cc * 160 + kw];
      *(u64*)((char*)WLh + cc * 1280 + ((kw * 8) ^ ((cc & 7) << 4))) = v;
    }
  }

  const int w  = tid >> 6;
  const int rf = w & 3;              // row-frag (16 rows)
  const int ch = w >> 2;             // col-half: 0 -> cf 0..2, 1 -> cf 3..4
  const int cf0 = ch ? 3 : 0;
  const int ncf = ch ? 2 : 3;
  const int l  = tid & 63;
  const int lr = l & 15;
  const int aq = l >> 4;
  const int arow = r0 + rf * 16 + lr;

  // ---- per-thread cells: up to 3 of (64 rows x 20 j), idx = tid + i*512
  float cq[3] = {0.f, 0.f, 0.f}, hq[3] = {0.f, 0.f, 0.f};
  float mxv[3] = {-INFINITY, -INFINITY, -INFINITY};
  float bsv[3][4];
  int lenv[3];
  #pragma unroll
  for (int i = 0; i < 3; ++i) {
    int idx = tid + i * 512;
    if (idx < 1280) {
      int r = idx / 20, jj = idx - (idx / 20) * 20;
      int j = ct * 20 + jj;
      lenv[i] = a.lens[r0 + r];
      #pragma unroll
      for (int g = 0; g < 4; ++g) bsv[i][g] = a.bsum[dir * 1200 + g * 300 + j];
    } else {
      lenv[i] = 0;
      bsv[i][0] = bsv[i][1] = bsv[i][2] = bsv[i][3] = 0.f;
    }
  }

  const int gi = dir * 8 + blockIdx.x;       // barrier group id (16 groups)
  int* cptr = a.cnt + gi * 64;
  int* fptr = a.cnt + gi * 64 + 16;
  __syncthreads();

  for (int s = 0; s < S_LEN; ++s) {
    const int tt  = dir ? (S_LEN - 1 - s) : s;
    const int cur = s & 1, nxt = cur ^ 1;

    f32x4 acc[3];
    #pragma unroll
    for (int i = 0; i < 3; ++i) acc[i] = (f32x4){0, 0, 0, 0};

    // ---- issue ALL h-frag loads first (latency hides under x segment)
    const u16* hrow = a.hbufH + (((size_t)cur * 2 + dir) * 512 + arow) * 320 + aq * 8;
    bf16x8 hf[10];
    #pragma unroll
    for (int ks = 0; ks < 10; ++ks) hf[ks] = *(const bf16x8*)(hrow + ks * 32);

    // ---- x segment: ks 0..9, A = bf16 direct, prefetch 1-deep
    {
      const u16* xrow = a.xallR + ((size_t)tt * 512 + arow) * 320 + aq * 8;
      bf16x8 Af = *(const bf16x8*)(xrow);
      #pragma unroll
      for (int ks = 0; ks < 10; ++ks) {
        bf16x8 An = (ks < 9) ? *(const bf16x8*)(xrow + (ks + 1) * 32) : Af;
        #pragma unroll
        for (int i = 0; i < 3; ++i) {
          if (i < ncf) {
            int cc = (cf0 + i) * 16 + lr;
            bf16x8 Bf = *(const bf16x8*)((const char*)WLh + cc * 1280 +
                                         ((ks * 64 + aq * 16) ^ ((cc & 7) << 4)));
            acc[i] = __builtin_amdgcn_mfma_f32_16x16x32_bf16(Af, Bf, acc[i], 0, 0, 0);
          }
        }
        Af = An;
      }
    }
    // ---- h segment: ks 10..19, A = preloaded bf16 frags
    #pragma unroll
    for (int ks = 0; ks < 10; ++ks) {
      #pragma unroll
      for (int i = 0; i < 3; ++i) {
        if (i < ncf) {
          int cc = (cf0 + i) * 16 + lr;
          bf16x8 Bf = *(const bf16x8*)((const char*)WLh + cc * 1280 +
                                       (((ks + 10) * 64 + aq * 16) ^ ((cc & 7) << 4)));
          acc[i] = __builtin_amdgcn_mfma_f32_16x16x32_bf16(hf[ks], Bf, acc[i], 0, 0, 0);
        }
      }
    }

    // ---- gate exchange: single write phase (C row=(l>>4)*4+reg, col=l&15)
    #pragma unroll
    for (int rr = 0; rr < 4; ++rr) {
      int gr = (rf * 16 + aq * 4 + rr) * 85;
      #pragma unroll
      for (int i = 0; i < 3; ++i) {
        if (i < ncf) Gs[gr + (cf0 + i) * 16 + lr] = acc[i][rr];
      }
    }
    __syncthreads();

    // ---- cell update (gate order i,f,g,o at cols jj*4+g)
    #pragma unroll
    for (int i = 0; i < 3; ++i) {
      int idx = tid + i * 512;
      if (idx < 1280) {
        int r = idx / 20, jj = idx - (idx / 20) * 20;
        bool m = tt < lenv[i];
        if (m) {
          float gi_ = Gs[r * 85 + jj * 4 + 0] + bsv[i][0];
          float gf  = Gs[r * 85 + jj * 4 + 1] + bsv[i][1];
          float gg  = Gs[r * 85 + jj * 4 + 2] + bsv[i][2];
          float go  = Gs[r * 85 + jj * 4 + 3] + bsv[i][3];
          cq[i] = sigm(gf) * cq[i] + sigm(gi_) * tanhf(gg);
          hq[i] = sigm(go) * tanhf(cq[i]);
          mxv[i] = fmaxf(mxv[i], hq[i]);
        } else {
          mxv[i] = fmaxf(mxv[i], 0.f);
        }
        a.hbufH[(((size_t)nxt * 2 + dir) * 512 + r0 + r) * 320 + ct * 20 + jj] = f2u(hq[i]);
      }
    }

    // ---- per-(dir,rowtile) group barrier: 15 arrivals, epoch flag
    __syncthreads();
    if (tid == 0) {
      __threadfence();
      int old = __hip_atomic_fetch_add(cptr, 1, __ATOMIC_ACQ_REL, __HIP_MEMORY_SCOPE_AGENT);
      if (old == GRPSZ * (s + 1) - 1) {
        __hip_atomic_store(fptr, s + 1, __ATOMIC_RELEASE, __HIP_MEMORY_SCOPE_AGENT);
      } else {
        while (__hip_atomic_load(fptr, __ATOMIC_ACQUIRE, __HIP_MEMORY_SCOPE_AGENT) < s + 1)
          __builtin_amdgcn_s_sleep(1);
      }
      __threadfence();
    }
    __syncthreads();
  }

  // ---- maxpool writeout
  #pragma unroll
  for (int i = 0; i < 3; ++i) {
    int idx = tid + i * 512;
    if (idx < 1280) {
      int r = idx / 20, jj = idx - (idx / 20) * 20;
      a.maxb[(size_t)(r0 + r) * 600 + dir * 300 + ct * 20 + jj] = mxv[i];
    }
  }
}

// ------------------------------------------------------------------
// s_utt = tanh(maxpl @ lin1_W^T + lin1_b)   [512,100]
// ------------------------------------------------------------------
__global__ __launch_bounds__(128) void sutt_k(const float* __restrict__ maxb,
                                              const float* __restrict__ W,
                                              const float* __restrict__ bb,
                                              float* __restrict__ sutt) {
  int b = blockIdx.x, tid = threadIdx.x;
  __shared__ float mx[600];
  for (int i = tid; i < 600; i += 128) mx[i] = maxb[b * 600 + i];
  __syncthreads();
  if (tid < 100) {
    float acc = bb[tid];
    const float* wr = W + tid * 600;
    for (int k = 0; k < 600; ++k) acc += mx[k] * wr[k];
    sutt[b * 100 + tid] = tanhf(acc);
  }
}

// ------------------------------------------------------------------
// GRU x-projection: xg[dir][t][row][300] f32 (incl. bih)
// ------------------------------------------------------------------
__global__ __launch_bounds__(256) void gxg3(const float* __restrict__ sutt,
                                            const float* __restrict__ Wf, const float* __restrict__ bf_,
                                            const float* __restrict__ Wb, const float* __restrict__ bb_,
                                            float* __restrict__ xg) {
  __shared__ float bts[32][101];
  int tid = threadIdx.x;
  int rt = blockIdx.x * 32, t = blockIdx.y, dir = blockIdx.z;
  int tin = dir ? (39 - t) : t;
  for (int idx = tid; idx < 3200; idx += 256) {
    int r = idx / 100, k = idx - r * 100, row = rt + r;
    float v = 0.f;
    if (row < BM1) {
      int srow = row + 1 - 40 + tin;
      if (srow >= 0) v = sutt[srow * 100 + k];
    }
    bts[r][k] = v;
  }
  __syncthreads();
  const float* Wm = dir ? Wb : Wf;
  const float* bm = dir ? bb_ : bf_;
  for (int o = tid; o < 9600; o += 256) {
    int r = o & 31, g = o >> 5;
    float acc = bm[g];
    const float* wr = Wm + g * 100;
    const float* br = bts[r];
    for (int k = 0; k < 100; ++k) acc += br[k] * wr[k];
    int row = rt + r;
    if (row < BM1) xg[(((size_t)dir * 40 + t) * BM1 + row) * 300 + g] = acc;
  }
}

// ------------------------------------------------------------------
// GRU scan v4 (validated r9)
// ------------------------------------------------------------------
struct Gru4Args {
  const float* wt;
  const float* bhh[2];
  const float* xg;
  float* memf; float* memb;
};

__global__ __launch_bounds__(512) void gru4(Gru4Args a) {
  __shared__ float WT[30000];
  __shared__ float hl[2][4][104];
  int tid = threadIdx.x, rt = blockIdx.x * 4, dir = blockIdx.y;
  const float* src = a.wt + dir * 30000;
  for (int i = tid; i < 30000; i += 512) WT[i] = src[i];
  for (int i = tid; i < 832; i += 512) ((float*)hl)[i] = 0.f;
  int r = tid / 100, j = tid - r * 100;
  int row = rt + r;
  bool act = (tid < 400) && (row < BM1);
  const float* bhh = a.bhh[dir];
  float xr = 0.f, xz = 0.f, xn = 0.f;
  if (act) {
    size_t xb = ((size_t)(dir * 40) * BM1 + row) * 300;
    xr = a.xg[xb + j]; xz = a.xg[xb + 100 + j]; xn = a.xg[xb + 200 + j];
  }
  float hprev = 0.f;
  __syncthreads();
  for (int t = 0; t < 40; ++t) {
    int nxt = (t + 1) & 1, cur = t & 1;
    float xr2 = 0.f, xz2 = 0.f, xn2 = 0.f;
    if (act && t < 39) {
      size_t xb = ((size_t)(dir * 40 + t + 1) * BM1 + row) * 300;
      xr2 = a.xg[xb + j]; xz2 = a.xg[xb + 100 + j]; xn2 = a.xg[xb + 200 + j];
    }
    float v = 0.f;
    if (act) {
      float hr = bhh[j], hz = bhh[100 + j], hn = bhh[200 + j];
      const float* w0 = WT + j;
      const float* hrow = hl[cur][r];
      for (int k = 0; k < 100; ++k) {
        float hv = hrow[k];
        hr += hv * w0[k * 100];
        hz += hv * w0[10000 + k * 100];
        hn += hv * w0[20000 + k * 100];
      }
      float rg_ = sigm(xr + hr), zg = sigm(xz + hz);
      float ng = tanhf(xn + rg_ * hn);
      v = (1.f - zg) * ng + zg * hprev;
      int tin = dir ? (39 - t) : t;
      (dir ? a.memb : a.memf)[((size_t)tin * BM1 + row) * 100 + j] = v;
    }
    if (tid < 400) hl[nxt][r][j] = v;
    hprev = v;
    __syncthreads();
    xr = xr2; xz = xz2; xn = xn2;
  }
}

// mem = bt + mem_f + mem_b
__global__ void memcomb(const float* __restrict__ memf, const float* __restrict__ memb,
                        const float* __restrict__ sutt, float* __restrict__ memm) {
  int idx = blockIdx.x * 256 + threadIdx.x;
  if (idx >= 40 * BM1 * 100) return;
  int j = idx % 100; int rem = idx / 100; int row = rem % BM1; int t = rem / BM1;
  float v = memf[idx] + memb[idx];
  int sidx = row + 1 - 40 + t;
  if (sidx >= 0) v += sutt[sidx * 100 + j];
  memm[idx] = v;
}

__global__ void epsinit(const float* __restrict__ sutt, float* __restrict__ eps) {
  int idx = blockIdx.x * 256 + threadIdx.x;
  if (idx < BM1 * 100) eps[idx] = sutt[idx + 100];
}

// attention scores + softmax -> gates + attn output (f32)
__global__ __launch_bounds__(64) void attnsc(const float* __restrict__ eps,
                                             const float* __restrict__ memm,
                                             float* __restrict__ gatesw,
                                             float* __restrict__ outat) {
  int row = blockIdx.x, k = threadIdx.x;
  __shared__ float el[100];
  for (int i = k; i < 100; i += 64) el[i] = eps[row * 100 + i];
  __syncthreads();
  float val = -INFINITY;
  if (k < 40) {
    if (row + 1 - 40 + k >= 0) {
      const float* mrow = memm + ((size_t)k * BM1 + row) * 100;
      float s = 0.f;
      for (int d = 0; d < 100; ++d) s += el[d] * mrow[d];
      val = s;
    } else val = -1e10f;
  }
  float mx = val;
  for (int off = 32; off > 0; off >>= 1) mx = fmaxf(mx, __shfl_xor(mx, off));
  float ex = (k < 40) ? expf(val - mx) : 0.f;
  float sm = ex;
  for (int off = 32; off > 0; off >>= 1) sm += __shfl_xor(sm, off);
  if (k < 40) {
    float sc = ex / sm;
    gatesw[k * BM1 + row] = sc;
    outat[row * 40 + k] = sc;
  }
}

// cr/cw precompute GEMM: grid (16, 40, 2)
__global__ __launch_bounds__(256) void crcw3(const float* __restrict__ memm,
                                             const float* __restrict__ Wr, const float* __restrict__ br,
                                             const float* __restrict__ Ww, const float* __restrict__ bw,
                                             float* __restrict__ crb, float* __restrict__ cwb) {
  __shared__ float ml[32][101];
  int tid = threadIdx.x;
  int rt = blockIdx.x * 32, t = blockIdx.y, which = blockIdx.z;
  for (int idx = tid; idx < 3200; idx += 256) {
    int r = idx / 100, k = idx - r * 100; int row = rt + r;
    ml[r][k] = (row < BM1) ? memm[((size_t)t * BM1 + row) * 100 + k] : 0.f;
  }
  __syncthreads();
  const float* Wm = which ? Ww : Wr;
  const float* bm = which ? bw : br;
  float* ob = which ? cwb : crb;
  for (int o = tid; o < 3200; o += 256) {
    int r = o & 31, hh = o >> 5;
    float acc = bm[hh];
    const float* wr = Wm + hh * 100;
    for (int k = 0; k < 100; ++k) acc += ml[r][k] * wr[k];
    int row = rt + r;
    if (row < BM1) ob[((size_t)t * BM1 + row) * 100 + hh] = acc;
  }
}

// ------------------------------------------------------------------
// AttnGRU scan v4 (validated r9)
// ------------------------------------------------------------------
struct Att4Args {
  const float* urT; const float* uT;
  const float* bur; const float* bu;
  const float* crb; const float* cwb;
  const float* gatesw; float* eps;
};

__global__ __launch_bounds__(512) void attscan4(Att4Args a) {
  __shared__ float UrT[10000];
  __shared__ float UT[10000];
  __shared__ float hl[2][4][104];
  int tid = threadIdx.x, rt = blockIdx.x * 4;
  for (int i = tid; i < 10000; i += 512) { UrT[i] = a.urT[i]; UT[i] = a.uT[i]; }
  for (int i = tid; i < 832; i += 512) ((float*)hl)[i] = 0.f;
  int r = tid / 100, j = tid - r * 100;
  int row = rt + r;
  bool act = (tid < 400) && (row < BM1);
  float cr = 0.f, cw = 0.f, gw = 0.f;
  if (act) {
    size_t ix = (size_t)row * 100 + j;
    cr = a.crb[ix]; cw = a.cwb[ix]; gw = a.gatesw[row];
  }
  float hprev = 0.f;
  __syncthreads();
  for (int t = 0; t < 40; ++t) {
    int nxt = (t + 1) & 1, cur = t & 1;
    float cr2 = 0.f, cw2 = 0.f, gw2 = 0.f;
    if (act && t < 39) {
      size_t ix = ((size_t)(t + 1) * BM1 + row) * 100 + j;
      cr2 = a.crb[ix]; cw2 = a.cwb[ix]; gw2 = a.gatesw[(t + 1) * BM1 + row];
    }
    float v = 0.f;
    if (act) {
      float hr = a.bur[j], hu = a.bu[j];
      const float* hrow = hl[cur][r];
      for (int k = 0; k < 100; ++k) {
        float hv = hrow[k];
        hr += hv * UrT[k * 100 + j];
        hu += hv * UT[k * 100 + j];
      }
      float rg_ = sigm(cr + hr);
      float ht = tanhf(cw + rg_ * hu);
      v = gw * ht + (1.f - gw) * hprev;
    }
    if (tid < 400) hl[nxt][r][j] = v;
    hprev = v;
    __syncthreads();
    cr = cr2; cw = cw2; gw = gw2;
  }
  if (act) a.eps[(size_t)row * 100 + j] += hprev;
}

// classifier -> f32
__global__ __launch_bounds__(64) void cls_k(const float* __restrict__ sutt,
                                            const float* __restrict__ eps,
                                            const float* __restrict__ cW, const float* __restrict__ cb,
                                            float* __restrict__ outp) {
  int b = blockIdx.x, j = threadIdx.x;
  __shared__ float sl[100];
  for (int i = j; i < 100; i += 64) sl[i] = (b == 0) ? sutt[i] : eps[(b - 1) * 100 + i];
  __syncthreads();
  float lg = -INFINITY;
  if (j < 7) {
    lg = cb[j];
    const float* wr = cW + j * 100;
    for (int k = 0; k < 100; ++k) lg += sl[k] * wr[k];
  }
  float mx = lg;
  for (int off = 32; off > 0; off >>= 1) mx = fmaxf(mx, __shfl_xor(mx, off));
  float ex = (j < 7) ? expf(lg - mx) : 0.f;
  float sm = ex;
  for (int off = 32; off > 0; off >>= 1) sm += __shfl_xor(sm, off);
  if (j < 7) outp[b * 7 + j] = lg - mx - logf(sm);
}

// ------------------------------------------------------------------
extern "C" void kernel_launch(void* const* d_in, const int* in_sizes, int n_in,
                              void* d_out, int out_size, void* d_ws, size_t ws_size,
                              hipStream_t stream) {
  (void)n_in; (void)out_size; (void)ws_size;

  bool sigOrder = (in_sizes[7] == 360000);   // r4 evidence: dict order

  const void *p_sents, *p_lens, *p_emb;
  const void *p_lWih_f, *p_lWhh_f, *p_lbih_f, *p_lbhh_f;
  const void *p_lWih_b, *p_lWhh_b, *p_lbih_b, *p_lbhh_b;
  const void *p_gWih_f, *p_gWhh_f, *p_gbih_f, *p_gbhh_f;
  const void *p_gWih_b, *p_gWhh_b, *p_gbih_b, *p_gbhh_b;
  const void *p_lin1W, *p_lin1b;
  const void *p_attWr, *p_attUr, *p_attW, *p_attU;
  const void *p_attbr, *p_attbur, *p_attbw, *p_attbu;
  const void *p_clsW, *p_clsb;

  p_sents = d_in[0]; p_lens = d_in[1]; p_emb = d_in[2];
  p_lWih_f = d_in[3]; p_lWhh_f = d_in[4]; p_lbih_f = d_in[5]; p_lbhh_f = d_in[6];
  if (sigOrder) {
    p_lWih_b = d_in[7];  p_lWhh_b = d_in[8];  p_lbih_b = d_in[9];  p_lbhh_b = d_in[10];
    p_lin1W  = d_in[11]; p_lin1b  = d_in[12];
    p_gWih_f = d_in[13]; p_gWhh_f = d_in[14]; p_gbih_f = d_in[15]; p_gbhh_f = d_in[16];
    p_gWih_b = d_in[17]; p_gWhh_b = d_in[18]; p_gbih_b = d_in[19]; p_gbhh_b = d_in[20];
    p_attWr  = d_in[21]; p_attbr  = d_in[22]; p_attUr  = d_in[23]; p_attbur = d_in[24];
    p_attW   = d_in[25]; p_attbw  = d_in[26]; p_attU   = d_in[27]; p_attbu  = d_in[28];
    p_clsW   = d_in[29]; p_clsb   = d_in[30];
  } else {
    p_gWih_f = d_in[7];  p_gWhh_f = d_in[8];  p_gbih_f = d_in[9];  p_gbhh_f = d_in[10];
    p_lWih_b = d_in[11]; p_lWhh_b = d_in[12]; p_lbih_b = d_in[13]; p_lbhh_b = d_in[14];
    p_gWih_b = d_in[15]; p_gWhh_b = d_in[16]; p_gbih_b = d_in[17]; p_gbhh_b = d_in[18];
    p_lin1W  = d_in[19]; p_lin1b  = d_in[20];
    p_attWr  = d_in[21]; p_attUr  = d_in[22]; p_attW   = d_in[23]; p_attU   = d_in[24];
    p_attbr  = d_in[25]; p_attbur = d_in[26]; p_attbw  = d_in[27]; p_attbu  = d_in[28];
    p_clsW   = d_in[29]; p_clsb   = d_in[30];
  }

  char* wp = (char*)d_ws;
  auto carve = [&](size_t bytes) {
    char* p = wp;
    wp += (bytes + 255) & ~(size_t)255;
    return p;
  };
  int*   flag  = (int*)  carve(256);
  int*   cnt   = (int*)  carve(4096);
  float* allf  = (float*)carve((size_t)NF_TOT * 4);
  float* wt    = (float*)carve((size_t)120000 * 4);
  u16*   wL2   = (u16*)  carve((size_t)1536000 * 2);
  float* bsum  = (float*)carve((size_t)2400 * 4);
  u16*   hbufH = (u16*)  carve((size_t)2 * 2 * 512 * 320 * 2);
  float* maxb  = (float*)carve((size_t)B_SZ * 600 * 4);
  float* sutt  = (float*)carve((size_t)B_SZ * 100 * 4);
  // big region: xallR (bf16, dead after lstm11) aliases xg+memf+memb
  size_t xg_sz   = (size_t)2 * 40 * BM1 * 300 * 4;
  size_t memf_sz = (size_t)40 * BM1 * 100 * 4;
  char*  big   = carve(xg_sz + 2 * memf_sz);
  u16*   xallR = (u16*)big;
  float* xg    = (float*)big;
  float* memf  = (float*)(big + xg_sz);
  float* memb  = (float*)(big + xg_sz + memf_sz);
  float* memm  = (float*)carve(memf_sz);
  float* gatesw= (float*)carve((size_t)40 * BM1 * 4);
  float* eps   = (float*)carve((size_t)BM1 * 100 * 4);
  float* crb   = xg;
  float* cwb   = xg + (size_t)40 * BM1 * 100;

  float* out_pred = (float*)d_out;
  float* out_attn = out_pred + (size_t)B_SZ * NC_;

  detect_k<<<1, 256, 0, stream>>>((const u32*)p_emb, flag);

  NormFArgs nf;
  {
    const void* srcs[NF_NSEG] = {
      p_lWih_f, p_lWhh_f, p_lWih_b, p_lWhh_b,
      p_lbih_f, p_lbhh_f, p_lbih_b, p_lbhh_b,
      p_gWih_f, p_gWhh_f, p_gbih_f, p_gbhh_f,
      p_gWih_b, p_gWhh_b, p_gbih_b, p_gbhh_b,
      p_lin1W,  p_lin1b,
      p_attWr,  p_attUr,  p_attW,   p_attU,
      p_attbr,  p_attbur, p_attbw,  p_attbu,
      p_clsW,   p_clsb };
    for (int i = 0; i < NF_NSEG; ++i) nf.src[i] = srcs[i];
    nf.flag = flag; nf.dst = allf;
  }
  norm_f32<<<2048, 256, 0, stream>>>(nf);
  transp_k<<<(120000 + 255) / 256, 256, 0, stream>>>(allf, wt);
  tr_lstm2<<<(1538400 + 255) / 256, 256, 0, stream>>>(allf, wL2, bsum);
  xgat2<<<dim3(8, 100), 256, 0, stream>>>((const int*)p_sents, p_emb, flag, xallR);

  hipMemsetAsync(cnt, 0, 4096, stream);
  hipMemsetAsync(hbufH, 0, (size_t)2 * 2 * 512 * 320 * 2, stream);

  Lstm11Args la;
  la.lens = (const int*)p_lens;
  la.xallR = xallR; la.wL2 = wL2; la.bsum = bsum;
  la.hbufH = hbufH; la.maxb = maxb; la.cnt = cnt;
  lstm11<<<dim3(8, 15, 2), 512, 0, stream>>>(la);

  sutt_k<<<512, 128, 0, stream>>>(maxb, allf + AF_LIN1W, allf + AF_LIN1B, sutt);

  gxg3<<<dim3(16, 40, 2), 256, 0, stream>>>(sutt,
      allf + AF_GWIH_F, allf + AF_GBIH_F,
      allf + AF_GWIH_B, allf + AF_GBIH_B, xg);

  Gru4Args ga;
  ga.wt = wt;
  ga.bhh[0] = allf + AF_GBHH_F; ga.bhh[1] = allf + AF_GBHH_B;
  ga.xg = xg; ga.memf = memf; ga.memb = memb;
  gru4<<<dim3(128, 2), 512, 0, stream>>>(ga);

  memcomb<<<(40 * BM1 * 100 + 255) / 256, 256, 0, stream>>>(memf, memb, sutt, memm);
  epsinit<<<(BM1 * 100 + 255) / 256, 256, 0, stream>>>(sutt, eps);

  for (int hop = 0; hop < NHOP; ++hop) {
    attnsc<<<BM1, 64, 0, stream>>>(eps, memm, gatesw, out_attn + (size_t)hop * BM1 * 40);
    crcw3<<<dim3(16, 40, 2), 256, 0, stream>>>(memm,
        allf + AF_ATTWR + hop * 10000, allf + AF_ATTBR + hop * 100,
        allf + AF_ATTW  + hop * 10000, allf + AF_ATTBW + hop * 100, crb, cwb);
    Att4Args aa;
    aa.urT = wt + 60000 + hop * 10000;
    aa.uT  = wt + 90000 + hop * 10000;
    aa.bur = allf + AF_ATTBUR + hop * 100;
    aa.bu  = allf + AF_ATTBU  + hop * 100;
    aa.crb = crb; aa.cwb = cwb;
    aa.gatesw = gatesw; aa.eps = eps;
    attscan4<<<128, 512, 0, stream>>>(aa);
  }

  cls_k<<<512, 64, 0, stream>>>(sutt, eps, allf + AF_CLSW, allf + AF_CLSB, out_pred);
}